// Round 8
// baseline (445.198 us; speedup 1.0000x reference)
//
#include <hip/hip_runtime.h>

#define NN 100000
#define NE 1600000
#define HID 128
#define KEXT 160            // padded K: 128 feat | 16 edge | deg | 1 | 14 zero
#define ROWB 320            // bytes per ext row (KEXT * 2)
#define NB 782              // coarse buckets = ceil(NN/128)
#define P1B 128             // phase-1 blocks
#define EPB ((NE + P1B - 1) / P1B)
#define BN_EPS 1e-5f

typedef __attribute__((ext_vector_type(8))) short bf16x8;
typedef __attribute__((ext_vector_type(4))) float f32x4;
typedef unsigned long long u64;

__device__ inline unsigned short f2bf(float x) {
  union { float f; unsigned u; } v; v.f = x;
  unsigned r = v.u + 0x7FFFu + ((v.u >> 16) & 1u);
  return (unsigned short)(r >> 16);
}
__device__ inline unsigned pk2(float a, float b) {
  return (unsigned)f2bf(a) | ((unsigned)f2bf(b) << 16);
}
__device__ inline float bflo(unsigned p) { return __uint_as_float(p << 16); }
__device__ inline float bfhi(unsigned p) { return __uint_as_float(p & 0xffff0000u); }

__device__ inline void gload_lds16(const void* g, void* l) {
  __builtin_amdgcn_global_load_lds((const __attribute__((address_space(1))) void*)g,
                                   (__attribute__((address_space(3))) void*)l, 16, 0, 0);
}

// ---------------- features f32 -> bf16 (25000 blocks) + wext (80 blocks) ----------------
__global__ __launch_bounds__(256) void fbw_k(const float* __restrict__ f,
                                             unsigned* __restrict__ fb,
                                             const float* __restrict__ W1,
                                             const float* __restrict__ Wb,
                                             const float* __restrict__ bb,
                                             const float* __restrict__ b1,
                                             const float* __restrict__ W2,
                                             const float* __restrict__ b2,
                                             unsigned short* __restrict__ W1e,
                                             unsigned short* __restrict__ W2e) {
  if (blockIdx.x < 25000) {
    int i = blockIdx.x * 256 + threadIdx.x;
    float2 v = ((const float2*)f)[i];
    fb[i] = pk2(v.x, v.y);
  } else {
    int idx = (blockIdx.x - 25000) * 256 + threadIdx.x;
    if (idx >= 128 * KEXT) return;
    int c = idx / KEXT, k = idx - c * KEXT;
    float v1 = 0.f, v2 = 0.f;
    if (k < 128) { v1 = W1[c * HID + k]; v2 = W2[c * HID + k]; }
    else if (k < 144) v1 = Wb[c * 16 + (k - 128)];
    else if (k == 144) v1 = bb[c];
    else if (k == 145) v1 = b1[c];
    if (k == 128) v2 = b2[c];
    W1e[idx] = f2bf(v1);
    W2e[idx] = f2bf(v2);
  }
}

// ---------------- bucket-level histogram (782 buckets) ----------------
__global__ __launch_bounds__(256) void bhist_k(const int* __restrict__ dst,
                                               int* __restrict__ bcnt) {
  __shared__ int bh[NB];
  int b0 = blockIdx.x * EPB, e1 = min(b0 + EPB, NE);
  for (int i = threadIdx.x; i < NB; i += 256) bh[i] = 0;
  __syncthreads();
  for (int e = b0 + threadIdx.x; e < e1; e += 256) atomicAdd(&bh[dst[e] >> 7], 1);
  __syncthreads();
  for (int i = threadIdx.x; i < NB; i += 256)
    if (bh[i]) atomicAdd(&bcnt[i], bh[i]);
}

// ---------------- bucket scan (single block) ----------------
__global__ __launch_bounds__(1024) void bscan_k(const int* __restrict__ bcnt,
                                                int* __restrict__ bbase,
                                                int* __restrict__ gcur,
                                                int* __restrict__ rs) {
  __shared__ int s[1024];
  int t = threadIdx.x;
  int x = (t < NB) ? bcnt[t] : 0;
  s[t] = x;
  __syncthreads();
  for (int off = 1; off < 1024; off <<= 1) {
    int v = (t >= off) ? s[t - off] : 0;
    __syncthreads();
    s[t] += v;
    __syncthreads();
  }
  if (t < NB) {
    int excl = s[t] - x;
    bbase[t] = excl;
    gcur[t] = excl;
  }
  if (t == NB - 1) bbase[NB] = s[t];
  if (t == 0) rs[NN] = NE;
}

// ---------------- phase 1: partition edges; stream ef -> bucketed bf16 copy ----------------
// stg u64: src[0:17) | dst[38:55).  efb: 8 u32 (16 bf16) per edge at the stg position.
__global__ __launch_bounds__(256) void part_k(const int* __restrict__ src,
                                              const int* __restrict__ dst,
                                              const float* __restrict__ ef,
                                              int* __restrict__ gcur,
                                              u64* __restrict__ stg,
                                              float4* __restrict__ efb) {
  __shared__ int hist[NB], base[NB];
  int b0 = blockIdx.x * EPB;
  int e1 = min(b0 + EPB, NE);
  for (int i = threadIdx.x; i < NB; i += 256) hist[i] = 0;
  __syncthreads();
  for (int e = b0 + threadIdx.x; e < e1; e += 256)
    atomicAdd(&hist[dst[e] >> 7], 1);
  __syncthreads();
  for (int i = threadIdx.x; i < NB; i += 256) {
    int c = hist[i];
    if (c) base[i] = atomicAdd(&gcur[i], c);
  }
  __syncthreads();
  for (int e = b0 + threadIdx.x; e < e1; e += 256) {
    int d = dst[e];
    int b = d >> 7;
    int p = atomicAdd(&base[b], 1);
    stg[p] = (u64)(unsigned)src[e] | ((u64)(unsigned)d << 38);
    const float4* efp = (const float4*)(ef + (size_t)e * 16);
    float4 e0 = efp[0], e1v = efp[1], e2 = efp[2], e3 = efp[3];
    float4 w0, w1;
    w0.x = __uint_as_float(pk2(e0.x, e0.y)); w0.y = __uint_as_float(pk2(e0.z, e0.w));
    w0.z = __uint_as_float(pk2(e1v.x, e1v.y)); w0.w = __uint_as_float(pk2(e1v.z, e1v.w));
    w1.x = __uint_as_float(pk2(e2.x, e2.y)); w1.y = __uint_as_float(pk2(e2.z, e2.w));
    w1.z = __uint_as_float(pk2(e3.x, e3.y)); w1.w = __uint_as_float(pk2(e3.z, e3.w));
    efb[(size_t)p * 2] = w0;
    efb[(size_t)p * 2 + 1] = w1;
  }
}

// ---------------- phase 2: in-bucket node sort; derives row_start in-LDS ----------------
// fin u64: src[0:17) | efbpos[17:38)
__global__ __launch_bounds__(256) void bsort_k(const u64* __restrict__ stg,
                                               const int* __restrict__ bbase,
                                               int* __restrict__ rs,
                                               u64* __restrict__ fin) {
  __shared__ int h[128], cur[128], sc[128];
  int b = blockIdx.x, n0 = b << 7, tid = threadIdx.x;
  int s0 = bbase[b], e1 = bbase[b + 1];
  if (tid < 128) h[tid] = 0;
  __syncthreads();
  for (int i = s0 + tid; i < e1; i += 256)
    atomicAdd(&h[(int)(stg[i] >> 38) & 127], 1);
  __syncthreads();
  if (tid < 128) sc[tid] = h[tid];
  __syncthreads();
  for (int off = 1; off < 128; off <<= 1) {
    int v = 0;
    if (tid < 128 && tid >= off) v = sc[tid - off];
    __syncthreads();
    if (tid < 128) sc[tid] += v;
    __syncthreads();
  }
  if (tid < 128) {
    int excl = sc[tid] - h[tid];
    cur[tid] = s0 + excl;
    int n = n0 + tid;
    if (n < NN) rs[n] = s0 + excl;
  }
  __syncthreads();
  for (int i = s0 + tid; i < e1; i += 256) {
    u64 pk = stg[i];
    int d = (int)(pk >> 38) & 127;
    int p = atomicAdd(&cur[d], 1);
    fin[p] = (pk & 0x1FFFF) | ((u64)(unsigned)i << 17);
  }
}

// ---------------- merged gather: feat mailbox + ef mailbox (8-wide ILP) ----------------
__global__ __launch_bounds__(256) void feg_k(const unsigned* __restrict__ fb,
                                             const int* __restrict__ rs,
                                             const u64* __restrict__ fin,
                                             const unsigned* __restrict__ efb,
                                             unsigned short* __restrict__ A1) {
  int wid = threadIdx.x >> 6, lane = threadIdx.x & 63;
  int node = blockIdx.x * 4 + wid;
  if (node >= NN) return;
  int start = rs[node], end = rs[node + 1];
  int j8 = lane & 7, es = lane >> 3;      // ef mapping: edge-slot es, dim-pair j8
  float ax0 = 0.f, ay0 = 0.f, ax1 = 0.f, ay1 = 0.f;
  float ax2 = 0.f, ay2 = 0.f, ax3 = 0.f, ay3 = 0.f;
  float ax4 = 0.f, ay4 = 0.f, ax5 = 0.f, ay5 = 0.f;
  float ax6 = 0.f, ay6 = 0.f, ax7 = 0.f, ay7 = 0.f;
  float efx = 0.f, efy = 0.f;
  int i = start;
  for (; i + 8 <= end; i += 8) {
    int sl = 0, el = 0;
    if (lane < 8) {
      u64 pk = fin[i + lane];
      sl = (int)(pk & 0x1FFFF);
      el = (int)((pk >> 17) & 0x1FFFFF);
    }
    int s0 = __shfl(sl, 0), s1 = __shfl(sl, 1), s2 = __shfl(sl, 2), s3 = __shfl(sl, 3);
    int s4 = __shfl(sl, 4), s5 = __shfl(sl, 5), s6 = __shfl(sl, 6), s7 = __shfl(sl, 7);
    int pes = __shfl(el, es);
    unsigned p0 = fb[s0 * 64 + lane];
    unsigned p1 = fb[s1 * 64 + lane];
    unsigned p2 = fb[s2 * 64 + lane];
    unsigned p3 = fb[s3 * 64 + lane];
    unsigned p4 = fb[s4 * 64 + lane];
    unsigned p5 = fb[s5 * 64 + lane];
    unsigned p6 = fb[s6 * 64 + lane];
    unsigned p7 = fb[s7 * 64 + lane];
    unsigned ev = efb[(size_t)pes * 8 + j8];
    ax0 += bflo(p0); ay0 += bfhi(p0);
    ax1 += bflo(p1); ay1 += bfhi(p1);
    ax2 += bflo(p2); ay2 += bfhi(p2);
    ax3 += bflo(p3); ay3 += bfhi(p3);
    ax4 += bflo(p4); ay4 += bfhi(p4);
    ax5 += bflo(p5); ay5 += bfhi(p5);
    ax6 += bflo(p6); ay6 += bfhi(p6);
    ax7 += bflo(p7); ay7 += bfhi(p7);
    efx += bflo(ev); efy += bfhi(ev);
  }
  for (; i < end; ++i) {
    int sl = 0, el = 0;
    if (lane == 0) {
      u64 pk = fin[i];
      sl = (int)(pk & 0x1FFFF);
      el = (int)((pk >> 17) & 0x1FFFFF);
    }
    int s0 = __shfl(sl, 0), e0 = __shfl(el, 0);
    unsigned p0 = fb[s0 * 64 + lane];
    ax0 += bflo(p0); ay0 += bfhi(p0);
    if (lane < 8) {
      unsigned ev = efb[(size_t)e0 * 8 + j8];
      efx += bflo(ev); efy += bfhi(ev);
    }
  }
  // reduce ef over the 8 edge-slots (lane bits 3..5)
  efx += __shfl_xor(efx, 8);  efy += __shfl_xor(efy, 8);
  efx += __shfl_xor(efx, 16); efy += __shfl_xor(efy, 16);
  efx += __shfl_xor(efx, 32); efy += __shfl_xor(efy, 32);
  float ax = ((ax0 + ax1) + (ax2 + ax3)) + ((ax4 + ax5) + (ax6 + ax7));
  float ay = ((ay0 + ay1) + (ay2 + ay3)) + ((ay4 + ay5) + (ay6 + ay7));
  char* rowp = (char*)A1 + (size_t)node * ROWB;
  *(unsigned*)(rowp + lane * 4) = pk2(ax, ay);
  if (lane < 8) {
    *(unsigned*)(rowp + 256 + 4 * j8) = pk2(efx, efy);
  } else if (lane < 16) {
    int j2 = lane - 8;
    *(unsigned*)(rowp + 288 + 4 * j2) =
        (j2 == 0) ? pk2((float)(end - start), 1.0f) : 0u;
  }
}

// ---------------- MFMA GEMM: out[i][c] = A[i][:160] . W[c][:160] (+F) ----------------
template <bool RES>
__global__ __launch_bounds__(256) void gemm_mfma(
    const unsigned short* __restrict__ A, const unsigned short* __restrict__ W,
    const float* __restrict__ F, unsigned short* __restrict__ outb,
    float* __restrict__ ssum, float* __restrict__ ssq) {
  __shared__ __align__(16) char sA[64 * ROWB];    // 20 KB
  __shared__ __align__(16) char sW[128 * ROWB];   // 40 KB

  const int tid = threadIdx.x;
  const int wid = tid >> 6, lane = tid & 63;
  const size_t r0 = (size_t)blockIdx.x * 64;

#pragma unroll
  for (int q = 0; q < 5; ++q) {
    int s = q * 256 + tid;
    int row = (s * 3277) >> 16;        // s/20
    int c = s - row * 20;
    int csrc = (c < 16) ? (c ^ (row & 7)) : (16 + ((c - 16) ^ (row & 3)));
    gload_lds16((const char*)A + (r0 + row) * ROWB + csrc * 16,
                sA + (size_t)(q * 256 + wid * 64) * 16);
  }
#pragma unroll
  for (int q = 0; q < 10; ++q) {
    int s = q * 256 + tid;
    int row = (s * 3277) >> 16;
    int c = s - row * 20;
    int csrc = (c < 16) ? (c ^ (row & 7)) : (16 + ((c - 16) ^ (row & 3)));
    gload_lds16((const char*)W + (size_t)row * ROWB + csrc * 16,
                sW + (size_t)(q * 256 + wid * 64) * 16);
  }
  __syncthreads();

  const int l15 = lane & 15;
  const int kgr = lane >> 4;            // 0..3
  const int arow = wid * 16 + l15;

  bf16x8 afrag[5];
#pragma unroll
  for (int ks = 0; ks < 5; ++ks) {
    int creq = ks * 4 + kgr;
    int csw = (creq < 16) ? (creq ^ (arow & 7)) : (16 + ((creq - 16) ^ (arow & 3)));
    afrag[ks] = *(const bf16x8*)(sA + arow * ROWB + csw * 16);
  }

  f32x4 acc[8];
#pragma unroll
  for (int ct = 0; ct < 8; ++ct) acc[ct] = (f32x4){0.f, 0.f, 0.f, 0.f};

#pragma unroll
  for (int ct = 0; ct < 8; ++ct) {
    int brow = ct * 16 + l15;
#pragma unroll
    for (int ks = 0; ks < 5; ++ks) {
      int creq = ks * 4 + kgr;
      int csw = (creq < 16) ? (creq ^ (brow & 7)) : (16 + ((creq - 16) ^ (brow & 3)));
      bf16x8 bfrag = *(const bf16x8*)(sW + brow * ROWB + csw * 16);
      acc[ct] = __builtin_amdgcn_mfma_f32_16x16x32_bf16(afrag[ks], bfrag, acc[ct], 0, 0, 0);
    }
  }

  const size_t orow0 = r0 + wid * 16 + kgr * 4;
  float cs[8], cq[8];
#pragma unroll
  for (int ct = 0; ct < 8; ++ct) {
    int col = ct * 16 + l15;
    float s_ = 0.f, q_ = 0.f;
#pragma unroll
    for (int r = 0; r < 4; ++r) {
      size_t row = orow0 + r;
      if (row < NN) {
        float v = acc[ct][r];
        if (RES) v += F[row * HID + col];
        outb[row * HID + col] = f2bf(v);
        s_ += v; q_ += v * v;
      }
    }
    cs[ct] = s_; cq[ct] = q_;
  }

#pragma unroll
  for (int ct = 0; ct < 8; ++ct) {
    cs[ct] += __shfl_xor(cs[ct], 16); cs[ct] += __shfl_xor(cs[ct], 32);
    cq[ct] += __shfl_xor(cq[ct], 16); cq[ct] += __shfl_xor(cq[ct], 32);
  }
  __syncthreads();
  float* red = (float*)sA;
  if (lane < 16) {
#pragma unroll
    for (int ct = 0; ct < 8; ++ct) {
      red[wid * 256 + ct * 16 + l15] = cs[ct];
      red[wid * 256 + 128 + ct * 16 + l15] = cq[ct];
    }
  }
  __syncthreads();
  if (tid < 128) {
    float s_ = red[tid] + red[256 + tid] + red[512 + tid] + red[768 + tid];
    float q_ = red[128 + tid] + red[384 + tid] + red[640 + tid] + red[896 + tid];
    atomicAdd(&ssum[tid], s_);
    atomicAdd(&ssq[tid], q_);
  }
}

// ---------------- BN+ReLU -> next-layer bf16 A (stats finalized per-block) ----------------
__global__ __launch_bounds__(256) void bn_apply_bf16(const unsigned* __restrict__ t,
                                                     const float* __restrict__ ssum,
                                                     const float* __restrict__ ssq,
                                                     const float* __restrict__ gamma,
                                                     const float* __restrict__ beta,
                                                     unsigned short* __restrict__ A2) {
  __shared__ float ssc[128], ssh[128];
  int tid = threadIdx.x;
  if (tid < 128) {
    const float invN = 1.f / (float)NN;
    float m = ssum[tid] * invN;
    float var = ssq[tid] * invN - m * m;
    float inv = rsqrtf(var + BN_EPS);
    float sc = gamma[tid] * inv;
    ssc[tid] = sc;
    ssh[tid] = beta[tid] - m * sc;
  }
  __syncthreads();
  int wid = tid >> 6, lane = tid & 63;
  size_t row = (size_t)blockIdx.x * 4 + wid;
  if (row >= NN) return;
  unsigned p = t[row * 64 + lane];
  int c = lane * 2;
  float x = fmaxf(0.f, fmaf(bflo(p), ssc[c], ssh[c]));
  float y = fmaxf(0.f, fmaf(bfhi(p), ssc[c + 1], ssh[c + 1]));
  unsigned* orow = (unsigned*)((char*)A2 + row * ROWB);
  orow[lane] = pk2(x, y);
  if (lane < 16) orow[64 + lane] = (lane == 0) ? 0x3F80u : 0u;
}

// ---------------- final BN+ReLU -> f32 out (stats finalized per-block) ----------------
__global__ __launch_bounds__(256) void bn_final_k(const unsigned* __restrict__ t,
                                                  const float* __restrict__ ssum,
                                                  const float* __restrict__ ssq,
                                                  const float* __restrict__ gamma,
                                                  const float* __restrict__ beta,
                                                  float* __restrict__ o) {
  __shared__ float ssc[128], ssh[128];
  int tid = threadIdx.x;
  if (tid < 128) {
    const float invN = 1.f / (float)NN;
    float m = ssum[tid] * invN;
    float var = ssq[tid] * invN - m * m;
    float inv = rsqrtf(var + BN_EPS);
    float sc = gamma[tid] * inv;
    ssc[tid] = sc;
    ssh[tid] = beta[tid] - m * sc;
  }
  __syncthreads();
  int i = blockIdx.x * 256 + tid;
  if (i >= NN * 64) return;
  unsigned p = t[i];
  int c = (i & 63) * 2;
  float2 v;
  v.x = fmaxf(0.f, fmaf(bflo(p), ssc[c], ssh[c]));
  v.y = fmaxf(0.f, fmaf(bfhi(p), ssc[c + 1], ssh[c + 1]));
  ((float2*)o)[i] = v;
}

extern "C" void kernel_launch(void* const* d_in, const int* in_sizes, int n_in,
                              void* d_out, int out_size, void* d_ws, size_t ws_size,
                              hipStream_t stream) {
  (void)in_sizes; (void)n_in; (void)out_size; (void)ws_size;
  const float* features   = (const float*)d_in[0];
  const float* edge_feats = (const float*)d_in[1];
  const int*   src        = (const int*)d_in[2];
  const int*   dst        = (const int*)d_in[3];
  const float* Wb         = (const float*)d_in[4];
  const float* bb         = (const float*)d_in[5];
  const float* W1         = (const float*)d_in[6];
  const float* b1         = (const float*)d_in[7];
  const float* W2         = (const float*)d_in[8];
  const float* b2         = (const float*)d_in[9];
  const float* gamma1     = (const float*)d_in[10];
  const float* beta1      = (const float*)d_in[11];
  const float* gamma2     = (const float*)d_in[12];
  const float* beta2      = (const float*)d_in[13];
  float* outp = (float*)d_out;

  char* wsb = (char*)d_ws;
  size_t off = 0;
  auto alloc = [&](size_t nbytes) -> void* {
    off = (off + 255) & ~(size_t)255;
    void* p = wsb + off;
    off += nbytes;
    return p;
  };
  int* row_start = (int*)alloc((size_t)(NN + 1) * 4);
  int* bcnt      = (int*)alloc(NB * 4);            // zero-block start
  int* bbase     = (int*)alloc((NB + 1) * 4);
  int* gcur      = (int*)alloc(NB * 4);
  float* stats   = (float*)alloc(512 * 4);          // zero-block end
  unsigned* featb = (unsigned*)alloc((size_t)NN * 64 * 4);        // reused as t-buffer
  unsigned short* A1e = (unsigned short*)alloc((size_t)100032 * ROWB);
  unsigned short* A2e = (unsigned short*)alloc((size_t)100032 * ROWB);
  unsigned short* W1e = (unsigned short*)alloc(128 * KEXT * 2);
  unsigned short* W2e = (unsigned short*)alloc(128 * KEXT * 2);
  u64* stg       = (u64*)alloc((size_t)NE * 8);
  u64* fin       = (u64*)alloc((size_t)NE * 8);
  float4* efb    = (float4*)alloc((size_t)NE * 32);
  unsigned short* tbuf = (unsigned short*)featb;  // alias: featb dead after feg

  size_t zlen = (size_t)((char*)(stats + 512) - (char*)bcnt);
  hipMemsetAsync(bcnt, 0, zlen, stream);
  hipMemsetAsync((char*)A1e + (size_t)NN * ROWB, 0, 32 * ROWB, stream);
  hipMemsetAsync((char*)A2e + (size_t)NN * ROWB, 0, 32 * ROWB, stream);

  fbw_k<<<25080, 256, 0, stream>>>(features, featb, W1, Wb, bb, b1, W2, b2, W1e, W2e);
  bhist_k<<<P1B, 256, 0, stream>>>(dst, bcnt);
  bscan_k<<<1, 1024, 0, stream>>>(bcnt, bbase, gcur, row_start);
  part_k<<<P1B, 256, 0, stream>>>(src, dst, edge_feats, gcur, stg, efb);
  bsort_k<<<NB, 256, 0, stream>>>(stg, bbase, row_start, fin);
  feg_k<<<25000, 256, 0, stream>>>(featb, row_start, fin, (const unsigned*)efb, A1e);

  gemm_mfma<false><<<1563, 256, 0, stream>>>(A1e, W1e, nullptr, tbuf,
                                             stats, stats + 128);
  bn_apply_bf16<<<25000, 256, 0, stream>>>((const unsigned*)tbuf, stats, stats + 128,
                                           gamma1, beta1, A2e);

  gemm_mfma<true><<<1563, 256, 0, stream>>>(A2e, W2e, features, tbuf,
                                            stats + 256, stats + 384);
  bn_final_k<<<25000, 256, 0, stream>>>((const unsigned*)tbuf, stats + 256, stats + 384,
                                        gamma2, beta2, outp);
}

// Round 9
// 378.365 us; speedup vs baseline: 1.1766x; 1.1766x over previous
//
#include <hip/hip_runtime.h>

#define NN 100000
#define NE 1600000
#define HID 128
#define KEXT 160            // padded K: 128 feat | 16 edge | deg | 1 | 14 zero
#define ROWB 320            // bytes per ext row (KEXT * 2)
#define NB 782              // coarse buckets = ceil(NN/128)
#define P2B 512             // partition blocks
#define EPB2 ((NE + P2B - 1) / P2B)   // 3125
#define BN_EPS 1e-5f

typedef __attribute__((ext_vector_type(8))) short bf16x8;
typedef __attribute__((ext_vector_type(4))) float f32x4;
typedef unsigned long long u64;

__device__ inline unsigned short f2bf(float x) {
  union { float f; unsigned u; } v; v.f = x;
  unsigned r = v.u + 0x7FFFu + ((v.u >> 16) & 1u);
  return (unsigned short)(r >> 16);
}
__device__ inline unsigned pk2(float a, float b) {
  return (unsigned)f2bf(a) | ((unsigned)f2bf(b) << 16);
}
__device__ inline float bflo(unsigned p) { return __uint_as_float(p << 16); }
__device__ inline float bfhi(unsigned p) { return __uint_as_float(p & 0xffff0000u); }

__device__ inline void gload_lds16(const void* g, void* l) {
  __builtin_amdgcn_global_load_lds((const __attribute__((address_space(1))) void*)g,
                                   (__attribute__((address_space(3))) void*)l, 16, 0, 0);
}

// ---------------- features f32 -> bf16 (25000 blocks) + wext (80 blocks) ----------------
__global__ __launch_bounds__(256) void fbw_k(const float* __restrict__ f,
                                             unsigned* __restrict__ fb,
                                             const float* __restrict__ W1,
                                             const float* __restrict__ Wb,
                                             const float* __restrict__ bb,
                                             const float* __restrict__ b1,
                                             const float* __restrict__ W2,
                                             const float* __restrict__ b2,
                                             unsigned short* __restrict__ W1e,
                                             unsigned short* __restrict__ W2e) {
  if (blockIdx.x < 25000) {
    int i = blockIdx.x * 256 + threadIdx.x;
    float2 v = ((const float2*)f)[i];
    fb[i] = pk2(v.x, v.y);
  } else {
    int idx = (blockIdx.x - 25000) * 256 + threadIdx.x;
    if (idx >= 128 * KEXT) return;
    int c = idx / KEXT, k = idx - c * KEXT;
    float v1 = 0.f, v2 = 0.f;
    if (k < 128) { v1 = W1[c * HID + k]; v2 = W2[c * HID + k]; }
    else if (k < 144) v1 = Wb[c * 16 + (k - 128)];
    else if (k == 144) v1 = bb[c];
    else if (k == 145) v1 = b1[c];
    if (k == 128) v2 = b2[c];
    W1e[idx] = f2bf(v1);
    W2e[idx] = f2bf(v2);
  }
}

// ---------------- pass 1: per-(block,bucket) counts, no global atomics ----------------
__global__ __launch_bounds__(512) void cnt_k(const int* __restrict__ dst,
                                             int* __restrict__ cnts) {
  __shared__ int bh[NB];
  int blk = blockIdx.x;
  int b0 = blk * EPB2, e1 = min(b0 + EPB2, NE);
  for (int i = threadIdx.x; i < NB; i += 512) bh[i] = 0;
  __syncthreads();
  for (int e = b0 + threadIdx.x; e < e1; e += 512) atomicAdd(&bh[dst[e] >> 7], 1);
  __syncthreads();
  for (int i = threadIdx.x; i < NB; i += 512) cnts[i * P2B + blk] = bh[i];
}

// ---------------- per-bucket prefix over blocks -> chunk bases + totals ----------------
__global__ __launch_bounds__(512) void cscan_k(int* __restrict__ cnts,
                                               int* __restrict__ bcnt) {
  __shared__ int s[512];
  int b = blockIdx.x, t = threadIdx.x;
  int x = cnts[b * P2B + t];
  s[t] = x;
  __syncthreads();
  for (int off = 1; off < 512; off <<= 1) {
    int v = (t >= off) ? s[t - off] : 0;
    __syncthreads();
    s[t] += v;
    __syncthreads();
  }
  cnts[b * P2B + t] = s[t] - x;
  if (t == 511) bcnt[b] = s[t];
}

// ---------------- bucket scan (single block) ----------------
__global__ __launch_bounds__(1024) void bscan_k(const int* __restrict__ bcnt,
                                                int* __restrict__ bbase,
                                                int* __restrict__ rs) {
  __shared__ int s[1024];
  int t = threadIdx.x;
  int x = (t < NB) ? bcnt[t] : 0;
  s[t] = x;
  __syncthreads();
  for (int off = 1; off < 1024; off <<= 1) {
    int v = (t >= off) ? s[t - off] : 0;
    __syncthreads();
    s[t] += v;
    __syncthreads();
  }
  if (t < NB) bbase[t] = s[t] - x;
  if (t == NB - 1) bbase[NB] = s[t];
  if (t == 0) rs[NN] = NE;
}

// ---------------- pass 2: scatter to precomputed chunk bases; stream ef->bf16 ----------------
// stg u64: src[0:17) | dst[38:55).  efb: 8 u32 (16 bf16) per edge at the stg position.
__global__ __launch_bounds__(512) void part2_k(const int* __restrict__ src,
                                               const int* __restrict__ dst,
                                               const float* __restrict__ ef,
                                               const int* __restrict__ bbase,
                                               const int* __restrict__ cnts,
                                               u64* __restrict__ stg,
                                               float4* __restrict__ efb) {
  __shared__ int hist[NB], base[NB];
  int blk = blockIdx.x;
  int b0 = blk * EPB2, e1 = min(b0 + EPB2, NE);
  for (int i = threadIdx.x; i < NB; i += 512) {
    hist[i] = 0;
    base[i] = bbase[i] + cnts[i * P2B + blk];
  }
  __syncthreads();
  for (int e = b0 + threadIdx.x; e < e1; e += 512) {
    int d = dst[e];
    int b = d >> 7;
    int p = base[b] + atomicAdd(&hist[b], 1);
    stg[p] = (u64)(unsigned)src[e] | ((u64)(unsigned)d << 38);
    const float4* efp = (const float4*)(ef + (size_t)e * 16);
    float4 e0 = efp[0], e1v = efp[1], e2 = efp[2], e3 = efp[3];
    float4 w0, w1;
    w0.x = __uint_as_float(pk2(e0.x, e0.y)); w0.y = __uint_as_float(pk2(e0.z, e0.w));
    w0.z = __uint_as_float(pk2(e1v.x, e1v.y)); w0.w = __uint_as_float(pk2(e1v.z, e1v.w));
    w1.x = __uint_as_float(pk2(e2.x, e2.y)); w1.y = __uint_as_float(pk2(e2.z, e2.w));
    w1.z = __uint_as_float(pk2(e3.x, e3.y)); w1.w = __uint_as_float(pk2(e3.z, e3.w));
    efb[(size_t)p * 2] = w0;
    efb[(size_t)p * 2 + 1] = w1;
  }
}

// ---------------- phase 2: in-bucket node sort; derives row_start in-LDS ----------------
// fin u64: src[0:17) | efbpos[17:38)
__global__ __launch_bounds__(256) void bsort_k(const u64* __restrict__ stg,
                                               const int* __restrict__ bbase,
                                               int* __restrict__ rs,
                                               u64* __restrict__ fin) {
  __shared__ int h[128], cur[128], sc[128];
  int b = blockIdx.x, n0 = b << 7, tid = threadIdx.x;
  int s0 = bbase[b], e1 = bbase[b + 1];
  if (tid < 128) h[tid] = 0;
  __syncthreads();
  for (int i = s0 + tid; i < e1; i += 256)
    atomicAdd(&h[(int)(stg[i] >> 38) & 127], 1);
  __syncthreads();
  if (tid < 128) sc[tid] = h[tid];
  __syncthreads();
  for (int off = 1; off < 128; off <<= 1) {
    int v = 0;
    if (tid < 128 && tid >= off) v = sc[tid - off];
    __syncthreads();
    if (tid < 128) sc[tid] += v;
    __syncthreads();
  }
  if (tid < 128) {
    int excl = sc[tid] - h[tid];
    cur[tid] = s0 + excl;
    int n = n0 + tid;
    if (n < NN) rs[n] = s0 + excl;
  }
  __syncthreads();
  for (int i = s0 + tid; i < e1; i += 256) {
    u64 pk = stg[i];
    int d = (int)(pk >> 38) & 127;
    int p = atomicAdd(&cur[d], 1);
    fin[p] = (pk & 0x1FFFF) | ((u64)(unsigned)i << 17);
  }
}

// ---------------- merged gather: feat mailbox + ef mailbox (8-wide ILP) ----------------
__global__ __launch_bounds__(256) void feg_k(const unsigned* __restrict__ fb,
                                             const int* __restrict__ rs,
                                             const u64* __restrict__ fin,
                                             const unsigned* __restrict__ efb,
                                             unsigned short* __restrict__ A1) {
  int wid = threadIdx.x >> 6, lane = threadIdx.x & 63;
  int node = blockIdx.x * 4 + wid;
  if (node >= NN) return;
  int start = rs[node], end = rs[node + 1];
  int j8 = lane & 7, es = lane >> 3;      // ef mapping: edge-slot es, dim-pair j8
  float ax0 = 0.f, ay0 = 0.f, ax1 = 0.f, ay1 = 0.f;
  float ax2 = 0.f, ay2 = 0.f, ax3 = 0.f, ay3 = 0.f;
  float ax4 = 0.f, ay4 = 0.f, ax5 = 0.f, ay5 = 0.f;
  float ax6 = 0.f, ay6 = 0.f, ax7 = 0.f, ay7 = 0.f;
  float efx = 0.f, efy = 0.f;
  int i = start;
  for (; i + 8 <= end; i += 8) {
    int sl = 0, el = 0;
    if (lane < 8) {
      u64 pk = fin[i + lane];
      sl = (int)(pk & 0x1FFFF);
      el = (int)((pk >> 17) & 0x1FFFFF);
    }
    int s0 = __shfl(sl, 0), s1 = __shfl(sl, 1), s2 = __shfl(sl, 2), s3 = __shfl(sl, 3);
    int s4 = __shfl(sl, 4), s5 = __shfl(sl, 5), s6 = __shfl(sl, 6), s7 = __shfl(sl, 7);
    int pes = __shfl(el, es);
    unsigned p0 = fb[s0 * 64 + lane];
    unsigned p1 = fb[s1 * 64 + lane];
    unsigned p2 = fb[s2 * 64 + lane];
    unsigned p3 = fb[s3 * 64 + lane];
    unsigned p4 = fb[s4 * 64 + lane];
    unsigned p5 = fb[s5 * 64 + lane];
    unsigned p6 = fb[s6 * 64 + lane];
    unsigned p7 = fb[s7 * 64 + lane];
    unsigned ev = efb[(size_t)pes * 8 + j8];
    ax0 += bflo(p0); ay0 += bfhi(p0);
    ax1 += bflo(p1); ay1 += bfhi(p1);
    ax2 += bflo(p2); ay2 += bfhi(p2);
    ax3 += bflo(p3); ay3 += bfhi(p3);
    ax4 += bflo(p4); ay4 += bfhi(p4);
    ax5 += bflo(p5); ay5 += bfhi(p5);
    ax6 += bflo(p6); ay6 += bfhi(p6);
    ax7 += bflo(p7); ay7 += bfhi(p7);
    efx += bflo(ev); efy += bfhi(ev);
  }
  for (; i < end; ++i) {
    int sl = 0, el = 0;
    if (lane == 0) {
      u64 pk = fin[i];
      sl = (int)(pk & 0x1FFFF);
      el = (int)((pk >> 17) & 0x1FFFFF);
    }
    int s0 = __shfl(sl, 0), e0 = __shfl(el, 0);
    unsigned p0 = fb[s0 * 64 + lane];
    ax0 += bflo(p0); ay0 += bfhi(p0);
    if (lane < 8) {
      unsigned ev = efb[(size_t)e0 * 8 + j8];
      efx += bflo(ev); efy += bfhi(ev);
    }
  }
  // reduce ef over the 8 edge-slots (lane bits 3..5)
  efx += __shfl_xor(efx, 8);  efy += __shfl_xor(efy, 8);
  efx += __shfl_xor(efx, 16); efy += __shfl_xor(efy, 16);
  efx += __shfl_xor(efx, 32); efy += __shfl_xor(efy, 32);
  float ax = ((ax0 + ax1) + (ax2 + ax3)) + ((ax4 + ax5) + (ax6 + ax7));
  float ay = ((ay0 + ay1) + (ay2 + ay3)) + ((ay4 + ay5) + (ay6 + ay7));
  char* rowp = (char*)A1 + (size_t)node * ROWB;
  *(unsigned*)(rowp + lane * 4) = pk2(ax, ay);
  if (lane < 8) {
    *(unsigned*)(rowp + 256 + 4 * j8) = pk2(efx, efy);
  } else if (lane < 16) {
    int j2 = lane - 8;
    *(unsigned*)(rowp + 288 + 4 * j2) =
        (j2 == 0) ? pk2((float)(end - start), 1.0f) : 0u;
  }
}

// ---------------- MFMA GEMM: out[i][c] = A[i][:160] . W[c][:160] (+F) ----------------
template <bool RES>
__global__ __launch_bounds__(256) void gemm_mfma(
    const unsigned short* __restrict__ A, const unsigned short* __restrict__ W,
    const float* __restrict__ F, unsigned short* __restrict__ outb,
    float* __restrict__ ssum, float* __restrict__ ssq) {
  __shared__ __align__(16) char sA[64 * ROWB];    // 20 KB
  __shared__ __align__(16) char sW[128 * ROWB];   // 40 KB

  const int tid = threadIdx.x;
  const int wid = tid >> 6, lane = tid & 63;
  const size_t r0 = (size_t)blockIdx.x * 64;

#pragma unroll
  for (int q = 0; q < 5; ++q) {
    int s = q * 256 + tid;
    int row = (s * 3277) >> 16;        // s/20
    int c = s - row * 20;
    int csrc = (c < 16) ? (c ^ (row & 7)) : (16 + ((c - 16) ^ (row & 3)));
    gload_lds16((const char*)A + (r0 + row) * ROWB + csrc * 16,
                sA + (size_t)(q * 256 + wid * 64) * 16);
  }
#pragma unroll
  for (int q = 0; q < 10; ++q) {
    int s = q * 256 + tid;
    int row = (s * 3277) >> 16;
    int c = s - row * 20;
    int csrc = (c < 16) ? (c ^ (row & 7)) : (16 + ((c - 16) ^ (row & 3)));
    gload_lds16((const char*)W + (size_t)row * ROWB + csrc * 16,
                sW + (size_t)(q * 256 + wid * 64) * 16);
  }
  __syncthreads();

  const int l15 = lane & 15;
  const int kgr = lane >> 4;            // 0..3
  const int arow = wid * 16 + l15;

  bf16x8 afrag[5];
#pragma unroll
  for (int ks = 0; ks < 5; ++ks) {
    int creq = ks * 4 + kgr;
    int csw = (creq < 16) ? (creq ^ (arow & 7)) : (16 + ((creq - 16) ^ (arow & 3)));
    afrag[ks] = *(const bf16x8*)(sA + arow * ROWB + csw * 16);
  }

  f32x4 acc[8];
#pragma unroll
  for (int ct = 0; ct < 8; ++ct) acc[ct] = (f32x4){0.f, 0.f, 0.f, 0.f};

#pragma unroll
  for (int ct = 0; ct < 8; ++ct) {
    int brow = ct * 16 + l15;
#pragma unroll
    for (int ks = 0; ks < 5; ++ks) {
      int creq = ks * 4 + kgr;
      int csw = (creq < 16) ? (creq ^ (brow & 7)) : (16 + ((creq - 16) ^ (brow & 3)));
      bf16x8 bfrag = *(const bf16x8*)(sW + brow * ROWB + csw * 16);
      acc[ct] = __builtin_amdgcn_mfma_f32_16x16x32_bf16(afrag[ks], bfrag, acc[ct], 0, 0, 0);
    }
  }

  const size_t orow0 = r0 + wid * 16 + kgr * 4;
  float cs[8], cq[8];
#pragma unroll
  for (int ct = 0; ct < 8; ++ct) {
    int col = ct * 16 + l15;
    float s_ = 0.f, q_ = 0.f;
#pragma unroll
    for (int r = 0; r < 4; ++r) {
      size_t row = orow0 + r;
      if (row < NN) {
        float v = acc[ct][r];
        if (RES) v += F[row * HID + col];
        outb[row * HID + col] = f2bf(v);
        s_ += v; q_ += v * v;
      }
    }
    cs[ct] = s_; cq[ct] = q_;
  }

#pragma unroll
  for (int ct = 0; ct < 8; ++ct) {
    cs[ct] += __shfl_xor(cs[ct], 16); cs[ct] += __shfl_xor(cs[ct], 32);
    cq[ct] += __shfl_xor(cq[ct], 16); cq[ct] += __shfl_xor(cq[ct], 32);
  }
  __syncthreads();
  float* red = (float*)sA;
  if (lane < 16) {
#pragma unroll
    for (int ct = 0; ct < 8; ++ct) {
      red[wid * 256 + ct * 16 + l15] = cs[ct];
      red[wid * 256 + 128 + ct * 16 + l15] = cq[ct];
    }
  }
  __syncthreads();
  if (tid < 128) {
    float s_ = red[tid] + red[256 + tid] + red[512 + tid] + red[768 + tid];
    float q_ = red[128 + tid] + red[384 + tid] + red[640 + tid] + red[896 + tid];
    atomicAdd(&ssum[tid], s_);
    atomicAdd(&ssq[tid], q_);
  }
}

// ---------------- BN+ReLU -> next-layer bf16 A (stats finalized per-block) ----------------
__global__ __launch_bounds__(256) void bn_apply_bf16(const unsigned* __restrict__ t,
                                                     const float* __restrict__ ssum,
                                                     const float* __restrict__ ssq,
                                                     const float* __restrict__ gamma,
                                                     const float* __restrict__ beta,
                                                     unsigned short* __restrict__ A2) {
  __shared__ float ssc[128], ssh[128];
  int tid = threadIdx.x;
  if (tid < 128) {
    const float invN = 1.f / (float)NN;
    float m = ssum[tid] * invN;
    float var = ssq[tid] * invN - m * m;
    float inv = rsqrtf(var + BN_EPS);
    float sc = gamma[tid] * inv;
    ssc[tid] = sc;
    ssh[tid] = beta[tid] - m * sc;
  }
  __syncthreads();
  int wid = tid >> 6, lane = tid & 63;
  size_t row = (size_t)blockIdx.x * 4 + wid;
  if (row >= NN) return;
  unsigned p = t[row * 64 + lane];
  int c = lane * 2;
  float x = fmaxf(0.f, fmaf(bflo(p), ssc[c], ssh[c]));
  float y = fmaxf(0.f, fmaf(bfhi(p), ssc[c + 1], ssh[c + 1]));
  unsigned* orow = (unsigned*)((char*)A2 + row * ROWB);
  orow[lane] = pk2(x, y);
  if (lane < 16) orow[64 + lane] = (lane == 0) ? 0x3F80u : 0u;
}

// ---------------- final BN+ReLU -> f32 out (stats finalized per-block) ----------------
__global__ __launch_bounds__(256) void bn_final_k(const unsigned* __restrict__ t,
                                                  const float* __restrict__ ssum,
                                                  const float* __restrict__ ssq,
                                                  const float* __restrict__ gamma,
                                                  const float* __restrict__ beta,
                                                  float* __restrict__ o) {
  __shared__ float ssc[128], ssh[128];
  int tid = threadIdx.x;
  if (tid < 128) {
    const float invN = 1.f / (float)NN;
    float m = ssum[tid] * invN;
    float var = ssq[tid] * invN - m * m;
    float inv = rsqrtf(var + BN_EPS);
    float sc = gamma[tid] * inv;
    ssc[tid] = sc;
    ssh[tid] = beta[tid] - m * sc;
  }
  __syncthreads();
  int i = blockIdx.x * 256 + tid;
  if (i >= NN * 64) return;
  unsigned p = t[i];
  int c = (i & 63) * 2;
  float2 v;
  v.x = fmaxf(0.f, fmaf(bflo(p), ssc[c], ssh[c]));
  v.y = fmaxf(0.f, fmaf(bfhi(p), ssc[c + 1], ssh[c + 1]));
  ((float2*)o)[i] = v;
}

extern "C" void kernel_launch(void* const* d_in, const int* in_sizes, int n_in,
                              void* d_out, int out_size, void* d_ws, size_t ws_size,
                              hipStream_t stream) {
  (void)in_sizes; (void)n_in; (void)out_size; (void)ws_size;
  const float* features   = (const float*)d_in[0];
  const float* edge_feats = (const float*)d_in[1];
  const int*   src        = (const int*)d_in[2];
  const int*   dst        = (const int*)d_in[3];
  const float* Wb         = (const float*)d_in[4];
  const float* bb         = (const float*)d_in[5];
  const float* W1         = (const float*)d_in[6];
  const float* b1         = (const float*)d_in[7];
  const float* W2         = (const float*)d_in[8];
  const float* b2         = (const float*)d_in[9];
  const float* gamma1     = (const float*)d_in[10];
  const float* beta1      = (const float*)d_in[11];
  const float* gamma2     = (const float*)d_in[12];
  const float* beta2      = (const float*)d_in[13];
  float* outp = (float*)d_out;

  char* wsb = (char*)d_ws;
  size_t off = 0;
  auto alloc = [&](size_t nbytes) -> void* {
    off = (off + 255) & ~(size_t)255;
    void* p = wsb + off;
    off += nbytes;
    return p;
  };
  int* row_start = (int*)alloc((size_t)(NN + 1) * 4);
  int* bcnt      = (int*)alloc(NB * 4);
  int* bbase     = (int*)alloc((NB + 1) * 4);
  int* cnts      = (int*)alloc((size_t)NB * P2B * 4);
  float* stats   = (float*)alloc(512 * 4);
  unsigned* featb = (unsigned*)alloc((size_t)NN * 64 * 4);        // reused as t-buffer
  unsigned short* A1e = (unsigned short*)alloc((size_t)100032 * ROWB);
  unsigned short* A2e = (unsigned short*)alloc((size_t)100032 * ROWB);
  unsigned short* W1e = (unsigned short*)alloc(128 * KEXT * 2);
  unsigned short* W2e = (unsigned short*)alloc(128 * KEXT * 2);
  u64* stg       = (u64*)alloc((size_t)NE * 8);
  u64* fin       = (u64*)alloc((size_t)NE * 8);
  float4* efb    = (float4*)alloc((size_t)NE * 32);
  unsigned short* tbuf = (unsigned short*)featb;  // alias: featb dead after feg

  hipMemsetAsync(stats, 0, 512 * 4, stream);
  hipMemsetAsync((char*)A1e + (size_t)NN * ROWB, 0, 32 * ROWB, stream);
  hipMemsetAsync((char*)A2e + (size_t)NN * ROWB, 0, 32 * ROWB, stream);

  fbw_k<<<25080, 256, 0, stream>>>(features, featb, W1, Wb, bb, b1, W2, b2, W1e, W2e);
  cnt_k<<<P2B, 512, 0, stream>>>(dst, cnts);
  cscan_k<<<NB, 512, 0, stream>>>(cnts, bcnt);
  bscan_k<<<1, 1024, 0, stream>>>(bcnt, bbase, row_start);
  part2_k<<<P2B, 512, 0, stream>>>(src, dst, edge_feats, bbase, cnts, stg, efb);
  bsort_k<<<NB, 256, 0, stream>>>(stg, bbase, row_start, fin);
  feg_k<<<25000, 256, 0, stream>>>(featb, row_start, fin, (const unsigned*)efb, A1e);

  gemm_mfma<false><<<1563, 256, 0, stream>>>(A1e, W1e, nullptr, tbuf,
                                             stats, stats + 128);
  bn_apply_bf16<<<25000, 256, 0, stream>>>((const unsigned*)tbuf, stats, stats + 128,
                                           gamma1, beta1, A2e);

  gemm_mfma<true><<<1563, 256, 0, stream>>>(A2e, W2e, features, tbuf,
                                            stats + 256, stats + 384);
  bn_final_k<<<25000, 256, 0, stream>>>((const unsigned*)tbuf, stats + 256, stats + 384,
                                        gamma2, beta2, outp);
}

// Round 10
// 373.620 us; speedup vs baseline: 1.1916x; 1.0127x over previous
//
#include <hip/hip_runtime.h>

#define NN 100000
#define NE 1600000
#define HID 128
#define KEXT 160            // padded K: 128 feat | 16 edge | deg | 1 | 14 zero
#define ROWB 320            // bytes per ext row (KEXT * 2)
#define NB 782              // coarse buckets = ceil(NN/128)
#define P2B 256             // partition blocks
#define EPB2 ((NE + P2B - 1) / P2B)   // 6250
#define BN_EPS 1e-5f

typedef __attribute__((ext_vector_type(8))) short bf16x8;
typedef __attribute__((ext_vector_type(4))) float f32x4;
typedef unsigned long long u64;

__device__ inline unsigned short f2bf(float x) {
  union { float f; unsigned u; } v; v.f = x;
  unsigned r = v.u + 0x7FFFu + ((v.u >> 16) & 1u);
  return (unsigned short)(r >> 16);
}
__device__ inline unsigned pk2(float a, float b) {
  return (unsigned)f2bf(a) | ((unsigned)f2bf(b) << 16);
}
__device__ inline float bflo(unsigned p) { return __uint_as_float(p << 16); }
__device__ inline float bfhi(unsigned p) { return __uint_as_float(p & 0xffff0000u); }

__device__ inline void gload_lds16(const void* g, void* l) {
  __builtin_amdgcn_global_load_lds((const __attribute__((address_space(1))) void*)g,
                                   (__attribute__((address_space(3))) void*)l, 16, 0, 0);
}

// ---------------- features f32 -> bf16 (25000 blocks) + wext (80 blocks) ----------------
__global__ __launch_bounds__(256) void fbw_k(const float* __restrict__ f,
                                             unsigned* __restrict__ fb,
                                             const float* __restrict__ W1,
                                             const float* __restrict__ Wb,
                                             const float* __restrict__ bb,
                                             const float* __restrict__ b1,
                                             const float* __restrict__ W2,
                                             const float* __restrict__ b2,
                                             unsigned short* __restrict__ W1e,
                                             unsigned short* __restrict__ W2e) {
  if (blockIdx.x < 25000) {
    int i = blockIdx.x * 256 + threadIdx.x;
    float2 v = ((const float2*)f)[i];
    fb[i] = pk2(v.x, v.y);
  } else {
    int idx = (blockIdx.x - 25000) * 256 + threadIdx.x;
    if (idx >= 128 * KEXT) return;
    int c = idx / KEXT, k = idx - c * KEXT;
    float v1 = 0.f, v2 = 0.f;
    if (k < 128) { v1 = W1[c * HID + k]; v2 = W2[c * HID + k]; }
    else if (k < 144) v1 = Wb[c * 16 + (k - 128)];
    else if (k == 144) v1 = bb[c];
    else if (k == 145) v1 = b1[c];
    if (k == 128) v2 = b2[c];
    W1e[idx] = f2bf(v1);
    W2e[idx] = f2bf(v2);
  }
}

// ---------------- pass 1: per-(block,bucket) raw counts ----------------
__global__ __launch_bounds__(1024) void cnt_k(const int* __restrict__ dst,
                                              int* __restrict__ cnts_s) {
  __shared__ int bh[NB];
  int blk = blockIdx.x;
  int b0 = blk * EPB2, e1 = min(b0 + EPB2, NE);
  for (int i = threadIdx.x; i < NB; i += 1024) bh[i] = 0;
  __syncthreads();
  for (int e = b0 + threadIdx.x; e < e1; e += 1024) atomicAdd(&bh[dst[e] >> 7], 1);
  __syncthreads();
  for (int i = threadIdx.x; i < NB; i += 1024) cnts_s[i * P2B + blk] = bh[i];
}

// ---------------- per-bucket scans: padded stg offsets, padded ef offsets, real total ----------------
__global__ __launch_bounds__(P2B) void cscan_k(int* __restrict__ cnts_s,
                                               int* __restrict__ cnts_e,
                                               int* __restrict__ bcnt_s,
                                               int* __restrict__ bcnt_e,
                                               int* __restrict__ bcnt_r) {
  __shared__ int s[P2B];
  int b = blockIdx.x, t = threadIdx.x;
  int x = cnts_s[b * P2B + t];
  int xs = (x + 7) & ~7;
  int xe = (x + 1) & ~1;
  // scan padded-stg
  s[t] = xs; __syncthreads();
  for (int off = 1; off < P2B; off <<= 1) {
    int v = (t >= off) ? s[t - off] : 0; __syncthreads();
    s[t] += v; __syncthreads();
  }
  cnts_s[b * P2B + t] = s[t] - xs;
  if (t == P2B - 1) bcnt_s[b] = s[t];
  __syncthreads();
  // scan padded-ef
  s[t] = xe; __syncthreads();
  for (int off = 1; off < P2B; off <<= 1) {
    int v = (t >= off) ? s[t - off] : 0; __syncthreads();
    s[t] += v; __syncthreads();
  }
  cnts_e[b * P2B + t] = s[t] - xe;
  if (t == P2B - 1) bcnt_e[b] = s[t];
  __syncthreads();
  // real total
  s[t] = x; __syncthreads();
  for (int off = 1; off < P2B; off <<= 1) {
    int v = (t >= off) ? s[t - off] : 0; __syncthreads();
    s[t] += v; __syncthreads();
  }
  if (t == P2B - 1) bcnt_r[b] = s[t];
}

// ---------------- bucket-level scans (single block): real, stg-padded, ef-padded ----------------
__global__ __launch_bounds__(1024) void bscan_k(const int* __restrict__ bcnt_r,
                                                const int* __restrict__ bcnt_s,
                                                const int* __restrict__ bcnt_e,
                                                int* __restrict__ bbase_r,
                                                int* __restrict__ bbase_s,
                                                int* __restrict__ bbase_e,
                                                int* __restrict__ rs) {
  __shared__ int s[1024];
  int t = threadIdx.x;
#pragma unroll
  for (int pass = 0; pass < 3; ++pass) {
    const int* in = (pass == 0) ? bcnt_r : (pass == 1) ? bcnt_s : bcnt_e;
    int* out = (pass == 0) ? bbase_r : (pass == 1) ? bbase_s : bbase_e;
    int x = (t < NB) ? in[t] : 0;
    s[t] = x; __syncthreads();
    for (int off = 1; off < 1024; off <<= 1) {
      int v = (t >= off) ? s[t - off] : 0; __syncthreads();
      s[t] += v; __syncthreads();
    }
    if (t < NB) out[t] = s[t] - x;
    if (t == NB - 1) out[NB] = s[t];
    __syncthreads();
  }
  if (t == 0) rs[NN] = NE;
}

// ---------------- pass 2: sector-aligned chunk scatter, ef->bf16 stream ----------------
// stg u64: src[0:17) | d7[17:24) | valid[24] | ge[25:46)
__global__ __launch_bounds__(1024) void part2_k(const int* __restrict__ src,
                                                const int* __restrict__ dst,
                                                const float* __restrict__ ef,
                                                const int* __restrict__ bbase_s,
                                                const int* __restrict__ bbase_e,
                                                const int* __restrict__ cnts_s,
                                                const int* __restrict__ cnts_e,
                                                u64* __restrict__ stg,
                                                float4* __restrict__ efb) {
  __shared__ int hist[NB], base_s[NB], base_e[NB];
  int blk = blockIdx.x;
  int b0 = blk * EPB2, e1 = min(b0 + EPB2, NE);
  for (int i = threadIdx.x; i < NB; i += 1024) {
    hist[i] = 0;
    base_s[i] = bbase_s[i] + cnts_s[i * P2B + blk];
    base_e[i] = bbase_e[i] + cnts_e[i * P2B + blk];
  }
  __syncthreads();
  for (int e = b0 + threadIdx.x; e < e1; e += 1024) {
    int d = dst[e];
    int b = d >> 7;
    int o = atomicAdd(&hist[b], 1);
    int gs = base_s[b] + o;
    int ge = base_e[b] + o;
    stg[gs] = (u64)(unsigned)src[e] | ((u64)(unsigned)(d & 127) << 17) |
              (1ULL << 24) | ((u64)(unsigned)ge << 25);
    const float4* efp = (const float4*)(ef + (size_t)e * 16);
    float4 e0 = efp[0], e1v = efp[1], e2 = efp[2], e3 = efp[3];
    float4 w0, w1;
    w0.x = __uint_as_float(pk2(e0.x, e0.y)); w0.y = __uint_as_float(pk2(e0.z, e0.w));
    w0.z = __uint_as_float(pk2(e1v.x, e1v.y)); w0.w = __uint_as_float(pk2(e1v.z, e1v.w));
    w1.x = __uint_as_float(pk2(e2.x, e2.y)); w1.y = __uint_as_float(pk2(e2.z, e2.w));
    w1.z = __uint_as_float(pk2(e3.x, e3.y)); w1.w = __uint_as_float(pk2(e3.z, e3.w));
    efb[(size_t)ge * 2] = w0;
    efb[(size_t)ge * 2 + 1] = w1;
  }
  __syncthreads();
  // pad-fill to sector boundaries (stg: mult of 8 recs; efb: mult of 2 recs)
  float4 z4 = make_float4(0.f, 0.f, 0.f, 0.f);
  for (int i = threadIdx.x; i < NB; i += 1024) {
    int c = hist[i];
    int cs = (c + 7) & ~7;
    for (int j = c; j < cs; ++j) stg[base_s[i] + j] = 0ULL;
    if (c & 1) {
      int ge = base_e[i] + c;
      efb[(size_t)ge * 2] = z4;
      efb[(size_t)ge * 2 + 1] = z4;
    }
  }
}

// ---------------- phase 2: in-bucket node sort; derives row_start in-LDS ----------------
// fin u64: src[0:17) | ge[17:38)
__global__ __launch_bounds__(256) void bsort_k(const u64* __restrict__ stg,
                                               const int* __restrict__ bbase_s,
                                               const int* __restrict__ bbase_r,
                                               int* __restrict__ rs,
                                               u64* __restrict__ fin) {
  __shared__ int h[128], cur[128], sc[128];
  int b = blockIdx.x, n0 = b << 7, tid = threadIdx.x;
  int s0p = bbase_s[b], e1p = bbase_s[b + 1];
  int s0r = bbase_r[b];
  if (tid < 128) h[tid] = 0;
  __syncthreads();
  for (int i = s0p + tid; i < e1p; i += 256) {
    u64 rec = stg[i];
    if ((rec >> 24) & 1) atomicAdd(&h[(int)(rec >> 17) & 127], 1);
  }
  __syncthreads();
  if (tid < 128) sc[tid] = h[tid];
  __syncthreads();
  for (int off = 1; off < 128; off <<= 1) {
    int v = 0;
    if (tid < 128 && tid >= off) v = sc[tid - off];
    __syncthreads();
    if (tid < 128) sc[tid] += v;
    __syncthreads();
  }
  if (tid < 128) {
    int excl = sc[tid] - h[tid];
    cur[tid] = s0r + excl;
    int n = n0 + tid;
    if (n < NN) rs[n] = s0r + excl;
  }
  __syncthreads();
  for (int i = s0p + tid; i < e1p; i += 256) {
    u64 rec = stg[i];
    if ((rec >> 24) & 1) {
      int d = (int)(rec >> 17) & 127;
      int p = atomicAdd(&cur[d], 1);
      fin[p] = (rec & 0x1FFFF) | (((rec >> 25) & 0x1FFFFF) << 17);
    }
  }
}

// ---------------- merged gather: feat mailbox + ef mailbox (8-wide ILP, XCD swizzle) ----------------
__global__ __launch_bounds__(256) void feg_k(const unsigned* __restrict__ fb,
                                             const int* __restrict__ rs,
                                             const u64* __restrict__ fin,
                                             const unsigned* __restrict__ efb,
                                             unsigned short* __restrict__ A1) {
  // bijective XCD-chunked swizzle: 25000 = 8 * 3125
  int bid = (int)(blockIdx.x & 7) * 3125 + (int)(blockIdx.x >> 3);
  int wid = threadIdx.x >> 6, lane = threadIdx.x & 63;
  int node = bid * 4 + wid;
  if (node >= NN) return;
  int start = rs[node], end = rs[node + 1];
  int j8 = lane & 7, es = lane >> 3;      // ef mapping: edge-slot es, dim-pair j8
  float ax0 = 0.f, ay0 = 0.f, ax1 = 0.f, ay1 = 0.f;
  float ax2 = 0.f, ay2 = 0.f, ax3 = 0.f, ay3 = 0.f;
  float ax4 = 0.f, ay4 = 0.f, ax5 = 0.f, ay5 = 0.f;
  float ax6 = 0.f, ay6 = 0.f, ax7 = 0.f, ay7 = 0.f;
  float efx = 0.f, efy = 0.f;
  int i = start;
  for (; i + 8 <= end; i += 8) {
    int sl = 0, el = 0;
    if (lane < 8) {
      u64 pk = fin[i + lane];
      sl = (int)(pk & 0x1FFFF);
      el = (int)((pk >> 17) & 0x1FFFFF);
    }
    int s0 = __shfl(sl, 0), s1 = __shfl(sl, 1), s2 = __shfl(sl, 2), s3 = __shfl(sl, 3);
    int s4 = __shfl(sl, 4), s5 = __shfl(sl, 5), s6 = __shfl(sl, 6), s7 = __shfl(sl, 7);
    int pes = __shfl(el, es);
    unsigned p0 = fb[s0 * 64 + lane];
    unsigned p1 = fb[s1 * 64 + lane];
    unsigned p2 = fb[s2 * 64 + lane];
    unsigned p3 = fb[s3 * 64 + lane];
    unsigned p4 = fb[s4 * 64 + lane];
    unsigned p5 = fb[s5 * 64 + lane];
    unsigned p6 = fb[s6 * 64 + lane];
    unsigned p7 = fb[s7 * 64 + lane];
    unsigned ev = efb[(size_t)pes * 8 + j8];
    ax0 += bflo(p0); ay0 += bfhi(p0);
    ax1 += bflo(p1); ay1 += bfhi(p1);
    ax2 += bflo(p2); ay2 += bfhi(p2);
    ax3 += bflo(p3); ay3 += bfhi(p3);
    ax4 += bflo(p4); ay4 += bfhi(p4);
    ax5 += bflo(p5); ay5 += bfhi(p5);
    ax6 += bflo(p6); ay6 += bfhi(p6);
    ax7 += bflo(p7); ay7 += bfhi(p7);
    efx += bflo(ev); efy += bfhi(ev);
  }
  for (; i < end; ++i) {
    int sl = 0, el = 0;
    if (lane == 0) {
      u64 pk = fin[i];
      sl = (int)(pk & 0x1FFFF);
      el = (int)((pk >> 17) & 0x1FFFFF);
    }
    int s0 = __shfl(sl, 0), e0 = __shfl(el, 0);
    unsigned p0 = fb[s0 * 64 + lane];
    ax0 += bflo(p0); ay0 += bfhi(p0);
    if (lane < 8) {
      unsigned ev = efb[(size_t)e0 * 8 + j8];
      efx += bflo(ev); efy += bfhi(ev);
    }
  }
  // reduce ef over the 8 edge-slots (lane bits 3..5)
  efx += __shfl_xor(efx, 8);  efy += __shfl_xor(efy, 8);
  efx += __shfl_xor(efx, 16); efy += __shfl_xor(efy, 16);
  efx += __shfl_xor(efx, 32); efy += __shfl_xor(efy, 32);
  float ax = ((ax0 + ax1) + (ax2 + ax3)) + ((ax4 + ax5) + (ax6 + ax7));
  float ay = ((ay0 + ay1) + (ay2 + ay3)) + ((ay4 + ay5) + (ay6 + ay7));
  char* rowp = (char*)A1 + (size_t)node * ROWB;
  *(unsigned*)(rowp + lane * 4) = pk2(ax, ay);
  if (lane < 8) {
    *(unsigned*)(rowp + 256 + 4 * j8) = pk2(efx, efy);
  } else if (lane < 16) {
    int j2 = lane - 8;
    *(unsigned*)(rowp + 288 + 4 * j2) =
        (j2 == 0) ? pk2((float)(end - start), 1.0f) : 0u;
  }
}

// ---------------- MFMA GEMM: out[i][c] = A[i][:160] . W[c][:160] (+F) ----------------
template <bool RES>
__global__ __launch_bounds__(256) void gemm_mfma(
    const unsigned short* __restrict__ A, const unsigned short* __restrict__ W,
    const float* __restrict__ F, unsigned short* __restrict__ outb,
    float* __restrict__ ssum, float* __restrict__ ssq) {
  __shared__ __align__(16) char sA[64 * ROWB];    // 20 KB
  __shared__ __align__(16) char sW[128 * ROWB];   // 40 KB

  const int tid = threadIdx.x;
  const int wid = tid >> 6, lane = tid & 63;
  const size_t r0 = (size_t)blockIdx.x * 64;

#pragma unroll
  for (int q = 0; q < 5; ++q) {
    int s = q * 256 + tid;
    int row = (s * 3277) >> 16;        // s/20
    int c = s - row * 20;
    int csrc = (c < 16) ? (c ^ (row & 7)) : (16 + ((c - 16) ^ (row & 3)));
    gload_lds16((const char*)A + (r0 + row) * ROWB + csrc * 16,
                sA + (size_t)(q * 256 + wid * 64) * 16);
  }
#pragma unroll
  for (int q = 0; q < 10; ++q) {
    int s = q * 256 + tid;
    int row = (s * 3277) >> 16;
    int c = s - row * 20;
    int csrc = (c < 16) ? (c ^ (row & 7)) : (16 + ((c - 16) ^ (row & 3)));
    gload_lds16((const char*)W + (size_t)row * ROWB + csrc * 16,
                sW + (size_t)(q * 256 + wid * 64) * 16);
  }
  __syncthreads();

  const int l15 = lane & 15;
  const int kgr = lane >> 4;            // 0..3
  const int arow = wid * 16 + l15;

  bf16x8 afrag[5];
#pragma unroll
  for (int ks = 0; ks < 5; ++ks) {
    int creq = ks * 4 + kgr;
    int csw = (creq < 16) ? (creq ^ (arow & 7)) : (16 + ((creq - 16) ^ (arow & 3)));
    afrag[ks] = *(const bf16x8*)(sA + arow * ROWB + csw * 16);
  }

  f32x4 acc[8];
#pragma unroll
  for (int ct = 0; ct < 8; ++ct) acc[ct] = (f32x4){0.f, 0.f, 0.f, 0.f};

#pragma unroll
  for (int ct = 0; ct < 8; ++ct) {
    int brow = ct * 16 + l15;
#pragma unroll
    for (int ks = 0; ks < 5; ++ks) {
      int creq = ks * 4 + kgr;
      int csw = (creq < 16) ? (creq ^ (brow & 7)) : (16 + ((creq - 16) ^ (brow & 3)));
      bf16x8 bfrag = *(const bf16x8*)(sW + brow * ROWB + csw * 16);
      acc[ct] = __builtin_amdgcn_mfma_f32_16x16x32_bf16(afrag[ks], bfrag, acc[ct], 0, 0, 0);
    }
  }

  const size_t orow0 = r0 + wid * 16 + kgr * 4;
  float cs[8], cq[8];
#pragma unroll
  for (int ct = 0; ct < 8; ++ct) {
    int col = ct * 16 + l15;
    float s_ = 0.f, q_ = 0.f;
#pragma unroll
    for (int r = 0; r < 4; ++r) {
      size_t row = orow0 + r;
      if (row < NN) {
        float v = acc[ct][r];
        if (RES) v += F[row * HID + col];
        outb[row * HID + col] = f2bf(v);
        s_ += v; q_ += v * v;
      }
    }
    cs[ct] = s_; cq[ct] = q_;
  }

#pragma unroll
  for (int ct = 0; ct < 8; ++ct) {
    cs[ct] += __shfl_xor(cs[ct], 16); cs[ct] += __shfl_xor(cs[ct], 32);
    cq[ct] += __shfl_xor(cq[ct], 16); cq[ct] += __shfl_xor(cq[ct], 32);
  }
  __syncthreads();
  float* red = (float*)sA;
  if (lane < 16) {
#pragma unroll
    for (int ct = 0; ct < 8; ++ct) {
      red[wid * 256 + ct * 16 + l15] = cs[ct];
      red[wid * 256 + 128 + ct * 16 + l15] = cq[ct];
    }
  }
  __syncthreads();
  if (tid < 128) {
    float s_ = red[tid] + red[256 + tid] + red[512 + tid] + red[768 + tid];
    float q_ = red[128 + tid] + red[384 + tid] + red[640 + tid] + red[896 + tid];
    atomicAdd(&ssum[tid], s_);
    atomicAdd(&ssq[tid], q_);
  }
}

// ---------------- BN+ReLU -> next-layer bf16 A (stats finalized per-block) ----------------
__global__ __launch_bounds__(256) void bn_apply_bf16(const unsigned* __restrict__ t,
                                                     const float* __restrict__ ssum,
                                                     const float* __restrict__ ssq,
                                                     const float* __restrict__ gamma,
                                                     const float* __restrict__ beta,
                                                     unsigned short* __restrict__ A2) {
  __shared__ float ssc[128], ssh[128];
  int tid = threadIdx.x;
  if (tid < 128) {
    const float invN = 1.f / (float)NN;
    float m = ssum[tid] * invN;
    float var = ssq[tid] * invN - m * m;
    float inv = rsqrtf(var + BN_EPS);
    float sc = gamma[tid] * inv;
    ssc[tid] = sc;
    ssh[tid] = beta[tid] - m * sc;
  }
  __syncthreads();
  int wid = tid >> 6, lane = tid & 63;
  size_t row = (size_t)blockIdx.x * 4 + wid;
  if (row >= NN) return;
  unsigned p = t[row * 64 + lane];
  int c = lane * 2;
  float x = fmaxf(0.f, fmaf(bflo(p), ssc[c], ssh[c]));
  float y = fmaxf(0.f, fmaf(bfhi(p), ssc[c + 1], ssh[c + 1]));
  unsigned* orow = (unsigned*)((char*)A2 + row * ROWB);
  orow[lane] = pk2(x, y);
  if (lane < 16) orow[64 + lane] = (lane == 0) ? 0x3F80u : 0u;
}

// ---------------- final BN+ReLU -> f32 out (stats finalized per-block) ----------------
__global__ __launch_bounds__(256) void bn_final_k(const unsigned* __restrict__ t,
                                                  const float* __restrict__ ssum,
                                                  const float* __restrict__ ssq,
                                                  const float* __restrict__ gamma,
                                                  const float* __restrict__ beta,
                                                  float* __restrict__ o) {
  __shared__ float ssc[128], ssh[128];
  int tid = threadIdx.x;
  if (tid < 128) {
    const float invN = 1.f / (float)NN;
    float m = ssum[tid] * invN;
    float var = ssq[tid] * invN - m * m;
    float inv = rsqrtf(var + BN_EPS);
    float sc = gamma[tid] * inv;
    ssc[tid] = sc;
    ssh[tid] = beta[tid] - m * sc;
  }
  __syncthreads();
  int i = blockIdx.x * 256 + tid;
  if (i >= NN * 64) return;
  unsigned p = t[i];
  int c = (i & 63) * 2;
  float2 v;
  v.x = fmaxf(0.f, fmaf(bflo(p), ssc[c], ssh[c]));
  v.y = fmaxf(0.f, fmaf(bfhi(p), ssc[c + 1], ssh[c + 1]));
  ((float2*)o)[i] = v;
}

extern "C" void kernel_launch(void* const* d_in, const int* in_sizes, int n_in,
                              void* d_out, int out_size, void* d_ws, size_t ws_size,
                              hipStream_t stream) {
  (void)in_sizes; (void)n_in; (void)out_size; (void)ws_size;
  const float* features   = (const float*)d_in[0];
  const float* edge_feats = (const float*)d_in[1];
  const int*   src        = (const int*)d_in[2];
  const int*   dst        = (const int*)d_in[3];
  const float* Wb         = (const float*)d_in[4];
  const float* bb         = (const float*)d_in[5];
  const float* W1         = (const float*)d_in[6];
  const float* b1         = (const float*)d_in[7];
  const float* W2         = (const float*)d_in[8];
  const float* b2         = (const float*)d_in[9];
  const float* gamma1     = (const float*)d_in[10];
  const float* beta1      = (const float*)d_in[11];
  const float* gamma2     = (const float*)d_in[12];
  const float* beta2      = (const float*)d_in[13];
  float* outp = (float*)d_out;

  char* wsb = (char*)d_ws;
  size_t off = 0;
  auto alloc = [&](size_t nbytes) -> void* {
    off = (off + 255) & ~(size_t)255;
    void* p = wsb + off;
    off += nbytes;
    return p;
  };
  int* row_start = (int*)alloc((size_t)(NN + 1) * 4);
  int* bcnt_r    = (int*)alloc(NB * 4);
  int* bcnt_s    = (int*)alloc(NB * 4);
  int* bcnt_e    = (int*)alloc(NB * 4);
  int* bbase_r   = (int*)alloc((NB + 1) * 4);
  int* bbase_s   = (int*)alloc((NB + 1) * 4);
  int* bbase_e   = (int*)alloc((NB + 1) * 4);
  int* cnts_s    = (int*)alloc((size_t)NB * P2B * 4);
  int* cnts_e    = (int*)alloc((size_t)NB * P2B * 4);
  float* stats   = (float*)alloc(512 * 4);
  unsigned* featb = (unsigned*)alloc((size_t)NN * 64 * 4);        // reused as t-buffer
  unsigned short* A1e = (unsigned short*)alloc((size_t)100032 * ROWB);
  unsigned short* W1e = (unsigned short*)alloc(128 * KEXT * 2);
  unsigned short* W2e = (unsigned short*)alloc(128 * KEXT * 2);
  u64* stg       = (u64*)alloc((size_t)(NE + 7 * NB * P2B + 64) * 8);   // padded (Q=8)
  u64* fin       = (u64*)alloc((size_t)NE * 8);
  float4* efb    = (float4*)alloc((size_t)(NE + NB * P2B + 64) * 32);   // padded (Q=2)
  unsigned short* tbuf = (unsigned short*)featb;  // alias: featb dead after feg
  unsigned short* A2e  = (unsigned short*)efb;    // alias: efb dead after feg

  hipMemsetAsync(stats, 0, 512 * 4, stream);
  hipMemsetAsync((char*)A1e + (size_t)NN * ROWB, 0, 32 * ROWB, stream);

  fbw_k<<<25080, 256, 0, stream>>>(features, featb, W1, Wb, bb, b1, W2, b2, W1e, W2e);
  cnt_k<<<P2B, 1024, 0, stream>>>(dst, cnts_s);
  cscan_k<<<NB, P2B, 0, stream>>>(cnts_s, cnts_e, bcnt_s, bcnt_e, bcnt_r);
  bscan_k<<<1, 1024, 0, stream>>>(bcnt_r, bcnt_s, bcnt_e, bbase_r, bbase_s, bbase_e,
                                  row_start);
  part2_k<<<P2B, 1024, 0, stream>>>(src, dst, edge_feats, bbase_s, bbase_e,
                                    cnts_s, cnts_e, stg, efb);
  bsort_k<<<NB, 256, 0, stream>>>(stg, bbase_s, bbase_r, row_start, fin);
  feg_k<<<25000, 256, 0, stream>>>(featb, row_start, fin, (const unsigned*)efb, A1e);

  gemm_mfma<false><<<1563, 256, 0, stream>>>(A1e, W1e, nullptr, tbuf,
                                             stats, stats + 128);
  // efb dead; zero A2e tail rows before it is used as GEMM-2 input
  hipMemsetAsync((char*)A2e + (size_t)NN * ROWB, 0, 32 * ROWB, stream);
  bn_apply_bf16<<<25000, 256, 0, stream>>>((const unsigned*)tbuf, stats, stats + 128,
                                           gamma1, beta1, A2e);

  gemm_mfma<true><<<1563, 256, 0, stream>>>(A2e, W2e, features, tbuf,
                                            stats + 256, stats + 384);
  bn_final_k<<<25000, 256, 0, stream>>>((const unsigned*)tbuf, stats + 256, stats + 384,
                                        gamma2, beta2, outp);
}

// Round 11
// 327.590 us; speedup vs baseline: 1.3590x; 1.1405x over previous
//
#include <hip/hip_runtime.h>

#define NN 100000
#define NE 1600000
#define HID 128
#define KEXT 160            // layer-1 K: 128 feat | 16 edge | deg | 1 | 14 zero
#define ROWB 320            // bytes per ext row (KEXT * 2)
#define BSH 9               // bucket shift: 512 nodes/bucket
#define BNODES 512
#define NB 196              // ceil(NN/512)
#define P2B 256             // partition blocks
#define EPB2 6250           // NE / P2B exact
#define T2 2048             // partition tile (edges)
#define BN_EPS 1e-5f

typedef __attribute__((ext_vector_type(8))) short bf16x8;
typedef __attribute__((ext_vector_type(4))) float f32x4;
typedef unsigned long long u64;

__device__ inline unsigned short f2bf(float x) {
  union { float f; unsigned u; } v; v.f = x;
  unsigned r = v.u + 0x7FFFu + ((v.u >> 16) & 1u);
  return (unsigned short)(r >> 16);
}
__device__ inline unsigned pk2(float a, float b) {
  return (unsigned)f2bf(a) | ((unsigned)f2bf(b) << 16);
}
__device__ inline float bflo(unsigned p) { return __uint_as_float(p << 16); }
__device__ inline float bfhi(unsigned p) { return __uint_as_float(p & 0xffff0000u); }

__device__ inline void gload_lds16(const void* g, void* l) {
  __builtin_amdgcn_global_load_lds((const __attribute__((address_space(1))) void*)g,
                                   (__attribute__((address_space(3))) void*)l, 16, 0, 0);
}

// ---------------- features f32 -> bf16 + weight prep ----------------
__global__ __launch_bounds__(256) void fbw_k(const float* __restrict__ f,
                                             unsigned* __restrict__ fb,
                                             const float* __restrict__ W1,
                                             const float* __restrict__ Wb,
                                             const float* __restrict__ bb,
                                             const float* __restrict__ b1,
                                             const float* __restrict__ W2,
                                             unsigned short* __restrict__ W1e,
                                             unsigned short* __restrict__ W2e) {
  if (blockIdx.x < 25000) {
    int i = blockIdx.x * 256 + threadIdx.x;
    float2 v = ((const float2*)f)[i];
    fb[i] = pk2(v.x, v.y);
  } else {
    int idx = (blockIdx.x - 25000) * 256 + threadIdx.x;
    if (idx < 128 * KEXT) {
      int c = idx / KEXT, k = idx - c * KEXT;
      float v1 = 0.f;
      if (k < 128) v1 = W1[c * HID + k];
      else if (k < 144) v1 = Wb[c * 16 + (k - 128)];
      else if (k == 144) v1 = bb[c];
      else if (k == 145) v1 = b1[c];
      W1e[idx] = f2bf(v1);
    }
    if (idx < 128 * 128) W2e[idx] = f2bf(W2[(idx >> 7) * HID + (idx & 127)]);
  }
}

// ---------------- pass 1: per-(block,bucket) raw counts ----------------
__global__ __launch_bounds__(1024) void cnt_k(const int* __restrict__ dst,
                                              int* __restrict__ cnts_s) {
  __shared__ int bh[NB];
  int blk = blockIdx.x;
  int b0 = blk * EPB2, e1 = b0 + EPB2;
  for (int i = threadIdx.x; i < NB; i += 1024) bh[i] = 0;
  __syncthreads();
  for (int e = b0 + threadIdx.x; e < e1; e += 1024) atomicAdd(&bh[dst[e] >> BSH], 1);
  __syncthreads();
  for (int i = threadIdx.x; i < NB; i += 1024) cnts_s[i * P2B + blk] = bh[i];
}

// ---------------- per-bucket scans over blocks: padded stg, padded ef, real ----------------
__global__ __launch_bounds__(P2B) void cscan_k(int* __restrict__ cnts_s,
                                               int* __restrict__ cnts_e,
                                               int* __restrict__ bcnt_s,
                                               int* __restrict__ bcnt_e,
                                               int* __restrict__ bcnt_r) {
  __shared__ int s[P2B];
  int b = blockIdx.x, t = threadIdx.x;
  int x = cnts_s[b * P2B + t];
  int xs = (x + 7) & ~7;
  int xe = (x + 1) & ~1;
  s[t] = xs; __syncthreads();
  for (int off = 1; off < P2B; off <<= 1) {
    int v = (t >= off) ? s[t - off] : 0; __syncthreads();
    s[t] += v; __syncthreads();
  }
  cnts_s[b * P2B + t] = s[t] - xs;
  if (t == P2B - 1) bcnt_s[b] = s[t];
  __syncthreads();
  s[t] = xe; __syncthreads();
  for (int off = 1; off < P2B; off <<= 1) {
    int v = (t >= off) ? s[t - off] : 0; __syncthreads();
    s[t] += v; __syncthreads();
  }
  cnts_e[b * P2B + t] = s[t] - xe;
  if (t == P2B - 1) bcnt_e[b] = s[t];
  __syncthreads();
  s[t] = x; __syncthreads();
  for (int off = 1; off < P2B; off <<= 1) {
    int v = (t >= off) ? s[t - off] : 0; __syncthreads();
    s[t] += v; __syncthreads();
  }
  if (t == P2B - 1) bcnt_r[b] = s[t];
}

// ---------------- bucket-level scans (single block) ----------------
__global__ __launch_bounds__(256) void bscan_k(const int* __restrict__ bcnt_r,
                                               const int* __restrict__ bcnt_s,
                                               const int* __restrict__ bcnt_e,
                                               int* __restrict__ bbase_r,
                                               int* __restrict__ bbase_s,
                                               int* __restrict__ bbase_e,
                                               int* __restrict__ rs) {
  __shared__ int s[256];
  int t = threadIdx.x;
#pragma unroll
  for (int pass = 0; pass < 3; ++pass) {
    const int* in = (pass == 0) ? bcnt_r : (pass == 1) ? bcnt_s : bcnt_e;
    int* out = (pass == 0) ? bbase_r : (pass == 1) ? bbase_s : bbase_e;
    int x = (t < NB) ? in[t] : 0;
    s[t] = x; __syncthreads();
    for (int off = 1; off < 256; off <<= 1) {
      int v = (t >= off) ? s[t - off] : 0; __syncthreads();
      s[t] += v; __syncthreads();
    }
    if (t < NB) out[t] = s[t] - x;
    if (t == NB - 1) out[NB] = s[t];
    __syncthreads();
  }
  if (t == 0) rs[NN] = NE;
}

// ---------------- pass 2: LDS counting-sort per tile -> coalesced chunk writes ----------------
// stg u64: src[0:17) | d9[17:26) | valid[26] | ge[27:48)
__global__ __launch_bounds__(1024) void part3_k(const int* __restrict__ src,
                                                const int* __restrict__ dst,
                                                const float* __restrict__ ef,
                                                const int* __restrict__ bbase_s,
                                                const int* __restrict__ bbase_e,
                                                const int* __restrict__ cnts_s,
                                                const int* __restrict__ cnts_e,
                                                u64* __restrict__ stg,
                                                float4* __restrict__ efb) {
  __shared__ int th[NB], ts[NB], cnt2[NB], run[NB], st_s[NB], st_e[NB];
  __shared__ int sscan[256];
  __shared__ unsigned spk[T2];
  __shared__ float4 eflds[T2 * 2];   // 64 KB
  int blk = blockIdx.x, tid = threadIdx.x;
  int b0 = blk * EPB2, e1 = b0 + EPB2;
  for (int i = tid; i < NB; i += 1024) {
    run[i] = 0;
    st_s[i] = bbase_s[i] + cnts_s[i * P2B + blk];
    st_e[i] = bbase_e[i] + cnts_e[i * P2B + blk];
  }
  for (int t0 = b0; t0 < e1; t0 += T2) {
    int tc = min(T2, e1 - t0);
    for (int i = tid; i < NB; i += 1024) { th[i] = 0; cnt2[i] = 0; }
    __syncthreads();
    // phase 0: histogram + stage ef (streamed, coalesced) -> LDS bf16
    for (int le = tid; le < tc; le += 1024) {
      int e = t0 + le;
      atomicAdd(&th[dst[e] >> BSH], 1);
      const float4* efp = (const float4*)(ef + (size_t)e * 16);
      float4 e0 = efp[0], e1v = efp[1], e2 = efp[2], e3 = efp[3];
      float4 w0, w1;
      w0.x = __uint_as_float(pk2(e0.x, e0.y));  w0.y = __uint_as_float(pk2(e0.z, e0.w));
      w0.z = __uint_as_float(pk2(e1v.x, e1v.y)); w0.w = __uint_as_float(pk2(e1v.z, e1v.w));
      w1.x = __uint_as_float(pk2(e2.x, e2.y));  w1.y = __uint_as_float(pk2(e2.z, e2.w));
      w1.z = __uint_as_float(pk2(e3.x, e3.y));  w1.w = __uint_as_float(pk2(e3.z, e3.w));
      eflds[le * 2] = w0;
      eflds[le * 2 + 1] = w1;
    }
    __syncthreads();
    // scan th -> ts (256-wide, NB<=256)
    if (tid < 256) sscan[tid] = (tid < NB) ? th[tid] : 0;
    __syncthreads();
    for (int off = 1; off < 256; off <<= 1) {
      int v = 0;
      if (tid < 256 && tid >= off) v = sscan[tid - off];
      __syncthreads();
      if (tid < 256) sscan[tid] += v;
      __syncthreads();
    }
    if (tid < NB) ts[tid] = sscan[tid] - th[tid];
    __syncthreads();
    // phase 1: slot assignment (sorted by bucket)
    for (int le = tid; le < tc; le += 1024) {
      int b = dst[t0 + le] >> BSH;
      int slot = ts[b] + atomicAdd(&cnt2[b], 1);
      spk[slot] = ((unsigned)b << 11) | (unsigned)le;
    }
    __syncthreads();
    // phase 2: emit in sorted order -> coalesced bucket-run writes
    for (int s2 = tid; s2 < tc; s2 += 1024) {
      unsigned pk = spk[s2];
      int b = pk >> 11, le = pk & 2047;
      int e = t0 + le;
      int o = run[b] + (s2 - ts[b]);
      int gs = st_s[b] + o;
      int ge = st_e[b] + o;
      int d9 = dst[e] & (BNODES - 1);
      stg[gs] = (u64)(unsigned)src[e] | ((u64)(unsigned)d9 << 17) |
                (1ULL << 26) | ((u64)(unsigned)ge << 27);
      efb[(size_t)ge * 2] = eflds[le * 2];
      efb[(size_t)ge * 2 + 1] = eflds[le * 2 + 1];
    }
    __syncthreads();
    for (int i = tid; i < NB; i += 1024) run[i] += th[i];
    __syncthreads();
  }
  // pad-fill to sector boundaries
  float4 z4 = make_float4(0.f, 0.f, 0.f, 0.f);
  for (int i = tid; i < NB; i += 1024) {
    int c = run[i];
    int cs = (c + 7) & ~7;
    for (int j = c; j < cs; ++j) stg[st_s[i] + j] = 0ULL;
    if (c & 1) {
      int ge = st_e[i] + c;
      efb[(size_t)ge * 2] = z4;
      efb[(size_t)ge * 2 + 1] = z4;
    }
  }
}

// ---------------- in-bucket node sort (512 nodes); derives row_start ----------------
// fin u64: src[0:17) | ge[17:38)
__global__ __launch_bounds__(512) void bsort_k(const u64* __restrict__ stg,
                                               const int* __restrict__ bbase_s,
                                               const int* __restrict__ bbase_r,
                                               int* __restrict__ rs,
                                               u64* __restrict__ fin) {
  __shared__ int h[BNODES], cur[BNODES], sc[BNODES];
  int b = blockIdx.x, n0 = b << BSH, tid = threadIdx.x;
  int s0p = bbase_s[b], e1p = bbase_s[b + 1];
  int s0r = bbase_r[b];
  h[tid] = 0;
  __syncthreads();
  for (int i = s0p + tid; i < e1p; i += 512) {
    u64 rec = stg[i];
    if ((rec >> 26) & 1) atomicAdd(&h[(int)(rec >> 17) & (BNODES - 1)], 1);
  }
  __syncthreads();
  sc[tid] = h[tid];
  __syncthreads();
  for (int off = 1; off < BNODES; off <<= 1) {
    int v = (tid >= off) ? sc[tid - off] : 0;
    __syncthreads();
    sc[tid] += v;
    __syncthreads();
  }
  {
    int excl = sc[tid] - h[tid];
    cur[tid] = s0r + excl;
    int n = n0 + tid;
    if (n < NN) rs[n] = s0r + excl;
  }
  __syncthreads();
  for (int i = s0p + tid; i < e1p; i += 512) {
    u64 rec = stg[i];
    if ((rec >> 26) & 1) {
      int d = (int)(rec >> 17) & (BNODES - 1);
      int p = atomicAdd(&cur[d], 1);
      fin[p] = (rec & 0x1FFFF) | (((rec >> 27) & 0x1FFFFF) << 17);
    }
  }
}

// ---------------- merged gather: feat mailbox + ef mailbox (8-wide ILP, XCD swizzle) ----------------
__global__ __launch_bounds__(256) void feg_k(const unsigned* __restrict__ fb,
                                             const int* __restrict__ rs,
                                             const u64* __restrict__ fin,
                                             const unsigned* __restrict__ efb,
                                             unsigned short* __restrict__ A1) {
  int bid = (int)(blockIdx.x & 7) * 3125 + (int)(blockIdx.x >> 3);
  int wid = threadIdx.x >> 6, lane = threadIdx.x & 63;
  int node = bid * 4 + wid;
  if (node >= NN) return;
  int start = rs[node], end = rs[node + 1];
  int j8 = lane & 7, es = lane >> 3;
  float ax0 = 0.f, ay0 = 0.f, ax1 = 0.f, ay1 = 0.f;
  float ax2 = 0.f, ay2 = 0.f, ax3 = 0.f, ay3 = 0.f;
  float ax4 = 0.f, ay4 = 0.f, ax5 = 0.f, ay5 = 0.f;
  float ax6 = 0.f, ay6 = 0.f, ax7 = 0.f, ay7 = 0.f;
  float efx = 0.f, efy = 0.f;
  int i = start;
  for (; i + 8 <= end; i += 8) {
    int sl = 0, el = 0;
    if (lane < 8) {
      u64 pk = fin[i + lane];
      sl = (int)(pk & 0x1FFFF);
      el = (int)((pk >> 17) & 0x1FFFFF);
    }
    int s0 = __shfl(sl, 0), s1 = __shfl(sl, 1), s2 = __shfl(sl, 2), s3 = __shfl(sl, 3);
    int s4 = __shfl(sl, 4), s5 = __shfl(sl, 5), s6 = __shfl(sl, 6), s7 = __shfl(sl, 7);
    int pes = __shfl(el, es);
    unsigned p0 = fb[s0 * 64 + lane];
    unsigned p1 = fb[s1 * 64 + lane];
    unsigned p2 = fb[s2 * 64 + lane];
    unsigned p3 = fb[s3 * 64 + lane];
    unsigned p4 = fb[s4 * 64 + lane];
    unsigned p5 = fb[s5 * 64 + lane];
    unsigned p6 = fb[s6 * 64 + lane];
    unsigned p7 = fb[s7 * 64 + lane];
    unsigned ev = efb[(size_t)pes * 8 + j8];
    ax0 += bflo(p0); ay0 += bfhi(p0);
    ax1 += bflo(p1); ay1 += bfhi(p1);
    ax2 += bflo(p2); ay2 += bfhi(p2);
    ax3 += bflo(p3); ay3 += bfhi(p3);
    ax4 += bflo(p4); ay4 += bfhi(p4);
    ax5 += bflo(p5); ay5 += bfhi(p5);
    ax6 += bflo(p6); ay6 += bfhi(p6);
    ax7 += bflo(p7); ay7 += bfhi(p7);
    efx += bflo(ev); efy += bfhi(ev);
  }
  for (; i < end; ++i) {
    int sl = 0, el = 0;
    if (lane == 0) {
      u64 pk = fin[i];
      sl = (int)(pk & 0x1FFFF);
      el = (int)((pk >> 17) & 0x1FFFFF);
    }
    int s0 = __shfl(sl, 0), e0 = __shfl(el, 0);
    unsigned p0 = fb[s0 * 64 + lane];
    ax0 += bflo(p0); ay0 += bfhi(p0);
    if (lane < 8) {
      unsigned ev = efb[(size_t)e0 * 8 + j8];
      efx += bflo(ev); efy += bfhi(ev);
    }
  }
  efx += __shfl_xor(efx, 8);  efy += __shfl_xor(efy, 8);
  efx += __shfl_xor(efx, 16); efy += __shfl_xor(efy, 16);
  efx += __shfl_xor(efx, 32); efy += __shfl_xor(efy, 32);
  float ax = ((ax0 + ax1) + (ax2 + ax3)) + ((ax4 + ax5) + (ax6 + ax7));
  float ay = ((ay0 + ay1) + (ay2 + ay3)) + ((ay4 + ay5) + (ay6 + ay7));
  char* rowp = (char*)A1 + (size_t)node * ROWB;
  *(unsigned*)(rowp + lane * 4) = pk2(ax, ay);
  if (lane < 8) {
    *(unsigned*)(rowp + 256 + 4 * j8) = pk2(efx, efy);
  } else if (lane < 16) {
    int j2 = lane - 8;
    *(unsigned*)(rowp + 288 + 4 * j2) =
        (j2 == 0) ? pk2((float)(end - start), 1.0f) : 0u;
  }
}

// ---------------- GEMM 1: tbuf[i][c] = A1[i][:160] . W1e[c][:160], stats ----------------
__global__ __launch_bounds__(256) void gemm1_k(
    const unsigned short* __restrict__ A, const unsigned short* __restrict__ W,
    unsigned short* __restrict__ outb, float* __restrict__ ssum, float* __restrict__ ssq) {
  __shared__ __align__(16) char sA[64 * ROWB];
  __shared__ __align__(16) char sW[128 * ROWB];
  const int tid = threadIdx.x;
  const int wid = tid >> 6, lane = tid & 63;
  const size_t r0 = (size_t)blockIdx.x * 64;

#pragma unroll
  for (int q = 0; q < 5; ++q) {
    int s = q * 256 + tid;
    int row = (s * 3277) >> 16;
    int c = s - row * 20;
    int csrc = (c < 16) ? (c ^ (row & 7)) : (16 + ((c - 16) ^ (row & 3)));
    gload_lds16((const char*)A + (r0 + row) * ROWB + csrc * 16,
                sA + (size_t)(q * 256 + wid * 64) * 16);
  }
#pragma unroll
  for (int q = 0; q < 10; ++q) {
    int s = q * 256 + tid;
    int row = (s * 3277) >> 16;
    int c = s - row * 20;
    int csrc = (c < 16) ? (c ^ (row & 7)) : (16 + ((c - 16) ^ (row & 3)));
    gload_lds16((const char*)W + (size_t)row * ROWB + csrc * 16,
                sW + (size_t)(q * 256 + wid * 64) * 16);
  }
  __syncthreads();

  const int l15 = lane & 15;
  const int kgr = lane >> 4;
  const int arow = wid * 16 + l15;
  bf16x8 afrag[5];
#pragma unroll
  for (int ks = 0; ks < 5; ++ks) {
    int creq = ks * 4 + kgr;
    int csw = (creq < 16) ? (creq ^ (arow & 7)) : (16 + ((creq - 16) ^ (arow & 3)));
    afrag[ks] = *(const bf16x8*)(sA + arow * ROWB + csw * 16);
  }
  f32x4 acc[8];
#pragma unroll
  for (int ct = 0; ct < 8; ++ct) acc[ct] = (f32x4){0.f, 0.f, 0.f, 0.f};
#pragma unroll
  for (int ct = 0; ct < 8; ++ct) {
    int brow = ct * 16 + l15;
#pragma unroll
    for (int ks = 0; ks < 5; ++ks) {
      int creq = ks * 4 + kgr;
      int csw = (creq < 16) ? (creq ^ (brow & 7)) : (16 + ((creq - 16) ^ (brow & 3)));
      bf16x8 bfrag = *(const bf16x8*)(sW + brow * ROWB + csw * 16);
      acc[ct] = __builtin_amdgcn_mfma_f32_16x16x32_bf16(afrag[ks], bfrag, acc[ct], 0, 0, 0);
    }
  }

  const size_t orow0 = r0 + wid * 16 + kgr * 4;
  float cs[8], cq[8];
#pragma unroll
  for (int ct = 0; ct < 8; ++ct) {
    int col = ct * 16 + l15;
    float s_ = 0.f, q_ = 0.f;
#pragma unroll
    for (int r = 0; r < 4; ++r) {
      size_t row = orow0 + r;
      if (row < NN) {
        float v = acc[ct][r];
        outb[row * HID + col] = f2bf(v);
        s_ += v; q_ += v * v;
      }
    }
    cs[ct] = s_; cq[ct] = q_;
  }
#pragma unroll
  for (int ct = 0; ct < 8; ++ct) {
    cs[ct] += __shfl_xor(cs[ct], 16); cs[ct] += __shfl_xor(cs[ct], 32);
    cq[ct] += __shfl_xor(cq[ct], 16); cq[ct] += __shfl_xor(cq[ct], 32);
  }
  __syncthreads();
  float* red = (float*)sA;
  if (lane < 16) {
#pragma unroll
    for (int ct = 0; ct < 8; ++ct) {
      red[wid * 256 + ct * 16 + l15] = cs[ct];
      red[wid * 256 + 128 + ct * 16 + l15] = cq[ct];
    }
  }
  __syncthreads();
  if (tid < 128) {
    float s_ = red[tid] + red[256 + tid] + red[512 + tid] + red[768 + tid];
    float q_ = red[128 + tid] + red[384 + tid] + red[640 + tid] + red[896 + tid];
    atomicAdd(&ssum[tid], s_);
    atomicAdd(&ssq[tid], q_);
  }
}

// ---------------- GEMM 2 (fused BN1+ReLU on A): out = relu(bn(t)) @ W2^T + b2 + F ----------------
__global__ __launch_bounds__(256) void gemm2_k(
    const unsigned* __restrict__ t, const unsigned short* __restrict__ W,
    const float* __restrict__ ssum, const float* __restrict__ ssq,
    const float* __restrict__ gamma, const float* __restrict__ beta,
    const float* __restrict__ b2, const float* __restrict__ F,
    unsigned short* __restrict__ outb, float* __restrict__ ssum2,
    float* __restrict__ ssq2) {
  __shared__ __align__(16) char sA[64 * 256];   // 16 KB
  __shared__ __align__(16) char sW[128 * 256];  // 32 KB
  __shared__ float ssc[128], ssh[128];
  const int tid = threadIdx.x;
  const int wid = tid >> 6, lane = tid & 63;
  const size_t r0 = (size_t)blockIdx.x * 64;

  if (tid < 128) {
    const float invN = 1.f / (float)NN;
    float m = ssum[tid] * invN;
    float var = ssq[tid] * invN - m * m;
    float inv = rsqrtf(var + BN_EPS);
    float sc = gamma[tid] * inv;
    ssc[tid] = sc;
    ssh[tid] = beta[tid] - m * sc;
  }
#pragma unroll
  for (int q = 0; q < 8; ++q) {
    int s = q * 256 + tid;
    int row = s >> 4, c = s & 15;
    int csrc = c ^ (row & 7);
    gload_lds16((const char*)W + (size_t)row * 256 + csrc * 16,
                sW + (size_t)(q * 256 + wid * 64) * 16);
  }
  __syncthreads();   // ssc visible; W staged

  // stage A with BN+ReLU transform: thread -> row tid>>2, chunks (tid&3)*4 ..+3
  {
    int sr = tid >> 2;
    int c0 = (tid & 3) * 4;
    size_t grow = r0 + sr;
    bool valid = grow < NN;
    const unsigned* trow = t + grow * 64;
#pragma unroll
    for (int cc = 0; cc < 4; ++cc) {
      int c = c0 + cc;
      unsigned o0 = 0, o1 = 0, o2 = 0, o3 = 0;
      if (valid) {
        unsigned p0 = trow[c * 4 + 0], p1 = trow[c * 4 + 1];
        unsigned p2 = trow[c * 4 + 2], p3 = trow[c * 4 + 3];
        int k = c * 8;
        o0 = pk2(fmaxf(0.f, fmaf(bflo(p0), ssc[k + 0], ssh[k + 0])),
                 fmaxf(0.f, fmaf(bfhi(p0), ssc[k + 1], ssh[k + 1])));
        o1 = pk2(fmaxf(0.f, fmaf(bflo(p1), ssc[k + 2], ssh[k + 2])),
                 fmaxf(0.f, fmaf(bfhi(p1), ssc[k + 3], ssh[k + 3])));
        o2 = pk2(fmaxf(0.f, fmaf(bflo(p2), ssc[k + 4], ssh[k + 4])),
                 fmaxf(0.f, fmaf(bfhi(p2), ssc[k + 5], ssh[k + 5])));
        o3 = pk2(fmaxf(0.f, fmaf(bflo(p3), ssc[k + 6], ssh[k + 6])),
                 fmaxf(0.f, fmaf(bfhi(p3), ssc[k + 7], ssh[k + 7])));
      }
      int csw = c ^ (sr & 7);
      uint4 w4; w4.x = o0; w4.y = o1; w4.z = o2; w4.w = o3;
      *(uint4*)(sA + sr * 256 + csw * 16) = w4;
    }
  }
  __syncthreads();

  const int l15 = lane & 15;
  const int kgr = lane >> 4;
  const int arow = wid * 16 + l15;
  bf16x8 afrag[4];
#pragma unroll
  for (int ks = 0; ks < 4; ++ks) {
    int creq = ks * 4 + kgr;
    int csw = creq ^ (arow & 7);
    afrag[ks] = *(const bf16x8*)(sA + arow * 256 + csw * 16);
  }
  f32x4 acc[8];
#pragma unroll
  for (int ct = 0; ct < 8; ++ct) acc[ct] = (f32x4){0.f, 0.f, 0.f, 0.f};
#pragma unroll
  for (int ct = 0; ct < 8; ++ct) {
    int brow = ct * 16 + l15;
#pragma unroll
    for (int ks = 0; ks < 4; ++ks) {
      int creq = ks * 4 + kgr;
      int csw = creq ^ (brow & 7);
      bf16x8 bfrag = *(const bf16x8*)(sW + brow * 256 + csw * 16);
      acc[ct] = __builtin_amdgcn_mfma_f32_16x16x32_bf16(afrag[ks], bfrag, acc[ct], 0, 0, 0);
    }
  }

  const size_t orow0 = r0 + wid * 16 + kgr * 4;
  float cs[8], cq[8];
#pragma unroll
  for (int ct = 0; ct < 8; ++ct) {
    int col = ct * 16 + l15;
    float b2v = b2[col];
    float s_ = 0.f, q_ = 0.f;
#pragma unroll
    for (int r = 0; r < 4; ++r) {
      size_t row = orow0 + r;
      if (row < NN) {
        float v = acc[ct][r] + b2v + F[row * HID + col];
        outb[row * HID + col] = f2bf(v);
        s_ += v; q_ += v * v;
      }
    }
    cs[ct] = s_; cq[ct] = q_;
  }
#pragma unroll
  for (int ct = 0; ct < 8; ++ct) {
    cs[ct] += __shfl_xor(cs[ct], 16); cs[ct] += __shfl_xor(cs[ct], 32);
    cq[ct] += __shfl_xor(cq[ct], 16); cq[ct] += __shfl_xor(cq[ct], 32);
  }
  __syncthreads();
  float* red = (float*)sA;
  if (lane < 16) {
#pragma unroll
    for (int ct = 0; ct < 8; ++ct) {
      red[wid * 256 + ct * 16 + l15] = cs[ct];
      red[wid * 256 + 128 + ct * 16 + l15] = cq[ct];
    }
  }
  __syncthreads();
  if (tid < 128) {
    float s_ = red[tid] + red[256 + tid] + red[512 + tid] + red[768 + tid];
    float q_ = red[128 + tid] + red[384 + tid] + red[640 + tid] + red[896 + tid];
    atomicAdd(&ssum2[tid], s_);
    atomicAdd(&ssq2[tid], q_);
  }
}

// ---------------- final BN+ReLU -> f32 out ----------------
__global__ __launch_bounds__(256) void bn_final_k(const unsigned* __restrict__ t,
                                                  const float* __restrict__ ssum,
                                                  const float* __restrict__ ssq,
                                                  const float* __restrict__ gamma,
                                                  const float* __restrict__ beta,
                                                  float* __restrict__ o) {
  __shared__ float ssc[128], ssh[128];
  int tid = threadIdx.x;
  if (tid < 128) {
    const float invN = 1.f / (float)NN;
    float m = ssum[tid] * invN;
    float var = ssq[tid] * invN - m * m;
    float inv = rsqrtf(var + BN_EPS);
    float sc = gamma[tid] * inv;
    ssc[tid] = sc;
    ssh[tid] = beta[tid] - m * sc;
  }
  __syncthreads();
  int i = blockIdx.x * 256 + tid;
  if (i >= NN * 64) return;
  unsigned p = t[i];
  int c = (i & 63) * 2;
  float2 v;
  v.x = fmaxf(0.f, fmaf(bflo(p), ssc[c], ssh[c]));
  v.y = fmaxf(0.f, fmaf(bfhi(p), ssc[c + 1], ssh[c + 1]));
  ((float2*)o)[i] = v;
}

extern "C" void kernel_launch(void* const* d_in, const int* in_sizes, int n_in,
                              void* d_out, int out_size, void* d_ws, size_t ws_size,
                              hipStream_t stream) {
  (void)in_sizes; (void)n_in; (void)out_size; (void)ws_size;
  const float* features   = (const float*)d_in[0];
  const float* edge_feats = (const float*)d_in[1];
  const int*   src        = (const int*)d_in[2];
  const int*   dst        = (const int*)d_in[3];
  const float* Wb         = (const float*)d_in[4];
  const float* bb         = (const float*)d_in[5];
  const float* W1         = (const float*)d_in[6];
  const float* b1         = (const float*)d_in[7];
  const float* W2         = (const float*)d_in[8];
  const float* b2         = (const float*)d_in[9];
  const float* gamma1     = (const float*)d_in[10];
  const float* beta1      = (const float*)d_in[11];
  const float* gamma2     = (const float*)d_in[12];
  const float* beta2      = (const float*)d_in[13];
  float* outp = (float*)d_out;

  char* wsb = (char*)d_ws;
  size_t off = 0;
  auto alloc = [&](size_t nbytes) -> void* {
    off = (off + 255) & ~(size_t)255;
    void* p = wsb + off;
    off += nbytes;
    return p;
  };
  int* row_start = (int*)alloc((size_t)(NN + 1) * 4);
  int* bcnt_r    = (int*)alloc(NB * 4);
  int* bcnt_s    = (int*)alloc(NB * 4);
  int* bcnt_e    = (int*)alloc(NB * 4);
  int* bbase_r   = (int*)alloc((NB + 1) * 4);
  int* bbase_s   = (int*)alloc((NB + 1) * 4);
  int* bbase_e   = (int*)alloc((NB + 1) * 4);
  int* cnts_s    = (int*)alloc((size_t)NB * P2B * 4);
  int* cnts_e    = (int*)alloc((size_t)NB * P2B * 4);
  float* stats   = (float*)alloc(512 * 4);
  unsigned* featb = (unsigned*)alloc((size_t)NN * 64 * 4);   // reused as t-buffer
  unsigned short* A1e = (unsigned short*)alloc((size_t)100032 * ROWB);
  unsigned short* W1e = (unsigned short*)alloc(128 * KEXT * 2);
  unsigned short* W2e = (unsigned short*)alloc(128 * 128 * 2);
  u64* stg       = (u64*)alloc((size_t)(NE + 7 * NB * P2B + 64) * 8);
  u64* fin       = (u64*)alloc((size_t)NE * 8);
  float4* efb    = (float4*)alloc((size_t)(NE + NB * P2B + 64) * 32);
  unsigned short* tbuf = (unsigned short*)featb;   // alias: featb dead after feg

  hipMemsetAsync(stats, 0, 512 * 4, stream);
  hipMemsetAsync((char*)A1e + (size_t)NN * ROWB, 0, 32 * ROWB, stream);

  fbw_k<<<25080, 256, 0, stream>>>(features, featb, W1, Wb, bb, b1, W2, W1e, W2e);
  cnt_k<<<P2B, 1024, 0, stream>>>(dst, cnts_s);
  cscan_k<<<NB, P2B, 0, stream>>>(cnts_s, cnts_e, bcnt_s, bcnt_e, bcnt_r);
  bscan_k<<<1, 256, 0, stream>>>(bcnt_r, bcnt_s, bcnt_e, bbase_r, bbase_s, bbase_e,
                                 row_start);
  part3_k<<<P2B, 1024, 0, stream>>>(src, dst, edge_feats, bbase_s, bbase_e,
                                    cnts_s, cnts_e, stg, efb);
  bsort_k<<<NB, 512, 0, stream>>>(stg, bbase_s, bbase_r, row_start, fin);
  feg_k<<<25000, 256, 0, stream>>>(featb, row_start, fin, (const unsigned*)efb, A1e);

  gemm1_k<<<1563, 256, 0, stream>>>(A1e, W1e, tbuf, stats, stats + 128);
  gemm2_k<<<1563, 256, 0, stream>>>((const unsigned*)tbuf, W2e, stats, stats + 128,
                                    gamma1, beta1, b2, features, tbuf,
                                    stats + 256, stats + 384);
  bn_final_k<<<25000, 256, 0, stream>>>((const unsigned*)tbuf, stats + 256, stats + 384,
                                        gamma2, beta2, outp);
}